// Round 2
// baseline (1028.219 us; speedup 1.0000x reference)
//
#include <hip/hip_runtime.h>
#include <hip/hip_bf16.h>
#include <math.h>

#define NN   100000
#define EE   1600000
#define ETOT 1700000   // EE + NN self loops
#define MM   40
#define HID  128
#define LAT  64
#define KS   32

typedef unsigned short u16;
typedef unsigned int   u32;

__device__ __forceinline__ float bf2f(u16 a) {
    return __uint_as_float(((u32)a) << 16);
}
__device__ __forceinline__ u16 f2bf(float f) {
    u32 u = __float_as_uint(f);
    u32 r = (u + 0x7fffu + ((u >> 16) & 1u)) >> 16;
    return (u16)r;
}

// packed f32 weight buffer offsets
#define OWp   0
#define Obp   5120
#define OW1l  5248
#define OW1r  21632
#define Oatt1 38016
#define Ob1   38144
#define OW2l  38272
#define OW2r  54656
#define Oatt2 71040
#define Ob2   71168
#define Og1   71296
#define Obe1  71424
#define Og2   71552
#define Obe2  71680
#define OWo   71808
#define Obo   80000
#define WTOT  80064

// ---------------- dtype sniff ----------------
// flags[0] = 1 if edge_index is int64; flags[1] = 1 if float inputs are bf16
__global__ void sniff_kernel(const u32* __restrict__ ei_raw, const u32* __restrict__ x_raw,
                             int* __restrict__ flags) {
    if (threadIdx.x != 0 || blockIdx.x != 0) return;
    int allz = 1;
    for (int i = 1; i < 256; i += 2) allz &= (ei_raw[i] == 0u);   // int64 high words
    flags[0] = allz;
    int bf_like = 0;
    for (int i = 0; i < 64; i++) {
        u16 lo = (u16)(x_raw[i] & 0xffffu);
        int e = (lo >> 7) & 0xFF;               // bf16 exponent field of the low halfword
        if (e >= 118 && e <= 133) bf_like++;    // N(0,1)-plausible magnitude
    }
    flags[1] = (bf_like >= 48) ? 1 : 0;
}

// ---------------- normalize x -> f32 ----------------
__global__ void normx_kernel(const void* __restrict__ in, float* __restrict__ out, int n,
                             const int* __restrict__ flags) {
    int i = blockIdx.x * 256 + threadIdx.x;
    if (i >= n) return;
    out[i] = flags[1] ? bf2f(((const u16*)in)[i]) : ((const float*)in)[i];
}

// ---------------- normalize all weights into packed f32 buffer ----------------
__global__ void norm_weights_kernel(
    const void* p0, const void* p1, const void* p2, const void* p3,
    const void* p4, const void* p5, const void* p6, const void* p7,
    const void* p8, const void* p9, const void* p10, const void* p11,
    const void* p12, const void* p13, const void* p14, const void* p15,
    float* __restrict__ out, const int* __restrict__ flags)
{
    int i = blockIdx.x * 256 + threadIdx.x;
    if (i >= WTOT) return;
    const int offs[17] = {OWp, Obp, OW1l, OW1r, Oatt1, Ob1, OW2l, OW2r,
                          Oatt2, Ob2, Og1, Obe1, Og2, Obe2, OWo, Obo, WTOT};
    const void* ps[16] = {p0,p1,p2,p3,p4,p5,p6,p7,p8,p9,p10,p11,p12,p13,p14,p15};
    int s = 0;
#pragma unroll
    for (int k = 1; k < 16; k++) s += (i >= offs[k]) ? 1 : 0;
    int j = i - offs[s];
    const void* p = ps[s];
    out[i] = flags[1] ? bf2f(((const u16*)p)[j]) : ((const float*)p)[j];
}

// ---------------- CSR build ----------------
__global__ void hist_kernel(const int* __restrict__ ei, const int* __restrict__ flags,
                            int* __restrict__ deg) {
    int e = blockIdx.x * 256 + threadIdx.x;
    if (e >= ETOT) return;
    int dst;
    if (e < EE) {
        int idx = EE + e;
        dst = flags[0] ? ei[2 * idx] : ei[idx];
    } else {
        dst = e - EE;
    }
    atomicAdd(&deg[dst], 1);
}

__global__ void scan_a(const int* __restrict__ deg, int* __restrict__ offs, int* __restrict__ bsum) {
    __shared__ int sc[256];
    int t = threadIdx.x;
    int base = blockIdx.x * 1024 + t * 4;
    int e[4];
#pragma unroll
    for (int j = 0; j < 4; j++) { int i = base + j; e[j] = (i < NN) ? deg[i] : 0; }
    int tsum = e[0] + e[1] + e[2] + e[3];
    sc[t] = tsum; __syncthreads();
    for (int d = 1; d < 256; d <<= 1) {
        int v = (t >= d) ? sc[t - d] : 0;
        __syncthreads();
        sc[t] += v;
        __syncthreads();
    }
    int run = (t == 0) ? 0 : sc[t - 1];
#pragma unroll
    for (int j = 0; j < 4; j++) { int i = base + j; if (i < NN) offs[i] = run; run += e[j]; }
    if (t == 255) bsum[blockIdx.x] = sc[255];
}

__global__ void scan_b(const int* __restrict__ bsum, int* __restrict__ bsumx, int nb) {
    __shared__ int sc[128];
    int t = threadIdx.x;
    sc[t] = (t < nb) ? bsum[t] : 0; __syncthreads();
    for (int d = 1; d < 128; d <<= 1) {
        int v = (t >= d) ? sc[t - d] : 0;
        __syncthreads();
        sc[t] += v;
        __syncthreads();
    }
    bsumx[t] = (t == 0) ? 0 : sc[t - 1];
}

__global__ void scan_c(int* __restrict__ offs, const int* __restrict__ bsumx, int* __restrict__ cursor) {
    int t = threadIdx.x, b = blockIdx.x;
    int add = bsumx[b];
    int base = b * 1024 + t * 4;
#pragma unroll
    for (int j = 0; j < 4; j++) {
        int i = base + j;
        if (i < NN) { int v = offs[i] + add; offs[i] = v; cursor[i] = v; }
    }
    if (b == 0 && t == 0) offs[NN] = ETOT;
}

__global__ void scatter_kernel(const int* __restrict__ ei, const int* __restrict__ flags,
                               int* __restrict__ cursor, int* __restrict__ srcs) {
    int e = blockIdx.x * 256 + threadIdx.x;
    if (e >= ETOT) return;
    int src, dst;
    if (e < EE) {
        src = flags[0] ? ei[2 * e] : ei[e];
        int idx = EE + e;
        dst = flags[0] ? ei[2 * idx] : ei[idx];
    } else {
        src = e - EE; dst = src;
    }
    int pos = atomicAdd(&cursor[dst], 1);
    srcs[pos] = src;
}

// ---------------- tiled GEMM: C[r,c] = sum_k A[r,k]*W[k,c] + bias[c] ----------------
// A: f32 [nrows,K]; W: f32 [K,WC]; C: f32 [nrows,WC] (or bf16 if final_out && flags[1])
__global__ __launch_bounds__(256) void gemm_kernel(
    const float* __restrict__ A, const float* __restrict__ W, const float* __restrict__ bias,
    void* __restrict__ C, int nrows, int K, int WC,
    int final_out, const int* __restrict__ flags)
{
    __shared__ float sAT[KS][132];   // [k][row], padded
    __shared__ float sW[KS][128];    // [k][col]
    int t = threadIdx.x;
    int tx = t & 15, ty = t >> 4;
    int r0 = blockIdx.x * 128;

    float acc[8][8];
#pragma unroll
    for (int i = 0; i < 8; i++)
#pragma unroll
        for (int j = 0; j < 8; j++) acc[i][j] = 0.f;

    for (int kb = 0; kb < K; kb += KS) {
        for (int idx = t; idx < 128 * KS; idx += 256) {
            int r = idx >> 5, kk = idx & 31;
            int gr = r0 + r, gk = kb + kk;
            float v = (gr < nrows && gk < K) ? A[(size_t)gr * K + gk] : 0.f;
            sAT[kk][r] = v;
        }
        for (int idx = t; idx < KS * 128; idx += 256) {
            int kk = idx >> 7, c = idx & 127;
            int gk = kb + kk;
            float v = (gk < K && c < WC) ? W[(size_t)gk * WC + c] : 0.f;
            sW[kk][c] = v;
        }
        __syncthreads();
#pragma unroll 4
        for (int k = 0; k < KS; ++k) {
            float4 a0 = *(const float4*)&sAT[k][ty * 4];
            float4 a1 = *(const float4*)&sAT[k][64 + ty * 4];
            float4 b0 = *(const float4*)&sW[k][tx * 4];
            float4 b1 = *(const float4*)&sW[k][64 + tx * 4];
            float av[8] = {a0.x, a0.y, a0.z, a0.w, a1.x, a1.y, a1.z, a1.w};
            float bv[8] = {b0.x, b0.y, b0.z, b0.w, b1.x, b1.y, b1.z, b1.w};
#pragma unroll
            for (int i = 0; i < 8; i++)
#pragma unroll
                for (int j = 0; j < 8; j++) acc[i][j] = fmaf(av[i], bv[j], acc[i][j]);
        }
        __syncthreads();
    }

    int out_bf16 = final_out ? flags[1] : 0;

    float bb[8];
#pragma unroll
    for (int j = 0; j < 8; j++) {
        int c = (j < 4) ? (tx * 4 + j) : (64 + tx * 4 + (j - 4));
        bb[j] = (bias != nullptr && c < WC) ? bias[c] : 0.f;
    }

#pragma unroll
    for (int i = 0; i < 8; i++) {
        int r = r0 + ((i < 4) ? (ty * 4 + i) : (64 + ty * 4 + (i - 4)));
        if (r >= nrows) continue;
#pragma unroll
        for (int g = 0; g < 2; g++) {
            int c = g * 64 + tx * 4;
            if (c >= WC) continue;
            int jb = g * 4;
            float v0 = acc[i][jb + 0] + bb[jb + 0];
            float v1 = acc[i][jb + 1] + bb[jb + 1];
            float v2 = acc[i][jb + 2] + bb[jb + 2];
            float v3 = acc[i][jb + 3] + bb[jb + 3];
            if (out_bf16) {
                ushort4 pk;
                pk.x = f2bf(v0); pk.y = f2bf(v1); pk.z = f2bf(v2); pk.w = f2bf(v3);
                *(ushort4*)&((u16*)C)[(size_t)r * WC + c] = pk;
            } else {
                *(float4*)&((float*)C)[(size_t)r * WC + c] = make_float4(v0, v1, v2, v3);
            }
        }
    }
}

// ---------------- fused GATv2 aggregation + bias + GELU + residual + LayerNorm ----------------
// one wave (64 lanes) per dst node; lane owns channels 2l, 2l+1 (head = lane/16)
__global__ __launch_bounds__(256) void gat_agg_kernel(
    const float* __restrict__ hl, const float* __restrict__ hr, const float* __restrict__ hres,
    const float* __restrict__ att, const float* __restrict__ bias,
    const float* __restrict__ gamma, const float* __restrict__ beta,
    const int* __restrict__ offs, const int* __restrict__ srcs,
    float* __restrict__ out)
{
    int dst  = (blockIdx.x * 256 + threadIdx.x) >> 6;   // grid sized so dst < NN exactly
    int lane = threadIdx.x & 63;
    int c = lane * 2;

    int start = offs[dst], end = offs[dst + 1];

    float2 hrv = *(const float2*)&hr[(size_t)dst * HID + c];
    float hrx = hrv.x, hry = hrv.y;
    float ax = att[c], ay = att[c + 1];

    float m = -INFINITY, s = 0.f, accx = 0.f, accy = 0.f;

    for (int e0 = start; e0 < end; e0 += 64) {
        int nb = end - e0; if (nb > 64) nb = 64;
        int mysrc = (lane < nb) ? srcs[e0 + lane] : 0;
        for (int j = 0; j < nb; ++j) {
            int src = __shfl(mysrc, j);
            float2 hv = *(const float2*)&hl[(size_t)src * HID + c];
            float hx = hv.x, hy = hv.y;
            float tx = hx + hrx, ty = hy + hry;
            float lx = tx > 0.f ? tx : 0.2f * tx;
            float ly = ty > 0.f ? ty : 0.2f * ty;
            float p = lx * ax + ly * ay;
            // reduce over the 16-lane head group
            p += __shfl_xor(p, 1); p += __shfl_xor(p, 2);
            p += __shfl_xor(p, 4); p += __shfl_xor(p, 8);
            // online softmax update
            float nm = fmaxf(m, p);
            float sc = __expf(m - nm);     // 0 on first edge (m = -inf)
            float w  = __expf(p - nm);
            s    = s * sc + w;
            accx = accx * sc + w * hx;
            accy = accy * sc + w * hy;
            m = nm;
        }
    }

    float inv = 1.f / s;
    float vx = accx * inv + bias[c];
    float vy = accy * inv + bias[c + 1];
    // exact GELU
    vx = 0.5f * vx * (1.f + erff(vx * 0.70710678118654752f));
    vy = 0.5f * vy * (1.f + erff(vy * 0.70710678118654752f));
    // residual
    float2 hv = *(const float2*)&hres[(size_t)dst * HID + c];
    vx += hv.x; vy += hv.y;
    // LayerNorm over 128 channels (whole wave)
    float s1 = vx + vy, s2 = vx * vx + vy * vy;
#pragma unroll
    for (int off = 1; off < 64; off <<= 1) {
        s1 += __shfl_xor(s1, off);
        s2 += __shfl_xor(s2, off);
    }
    float mu  = s1 * (1.f / 128.f);
    float var = s2 * (1.f / 128.f) - mu * mu;
    float rstd = rsqrtf(var + 1e-5f);
    float ox = (vx - mu) * rstd * gamma[c]     + beta[c];
    float oy = (vy - mu) * rstd * gamma[c + 1] + beta[c + 1];
    *(float2*)&out[(size_t)dst * HID + c] = make_float2(ox, oy);
}

// ---------------- launch ----------------
extern "C" void kernel_launch(void* const* d_in, const int* in_sizes, int n_in,
                              void* d_out, int out_size, void* d_ws, size_t ws_size,
                              hipStream_t stream) {
    const void* x    = d_in[0];
    const int*  ei   = (const int*)d_in[1];

    char* ws = (char*)d_ws;
    size_t off = 0;
    auto alloc = [&](size_t bytes) -> void* {
        void* p = ws + off;
        off = (off + bytes + 511) & ~(size_t)511;
        return p;
    };
    float* xf     = (float*)alloc((size_t)NN * MM  * 4);
    float* wpk    = (float*)alloc((size_t)WTOT * 4);
    float* h0     = (float*)alloc((size_t)NN * HID * 4);
    float* h1     = (float*)alloc((size_t)NN * HID * 4);
    float* hl     = (float*)alloc((size_t)NN * HID * 4);
    float* hr     = (float*)alloc((size_t)NN * HID * 4);
    int*   offs   = (int*)  alloc((size_t)(NN + 1) * 4);
    int*   cursor = (int*)  alloc((size_t)NN * 4);
    int*   deg    = (int*)  alloc((size_t)NN * 4);
    int*   bsum   = (int*)  alloc(512);
    int*   bsumx  = (int*)  alloc(512);
    int*   flags  = (int*)  alloc(512);
    int*   srcs   = (int*)  alloc((size_t)ETOT * 4);

    hipMemsetAsync(deg, 0, (size_t)NN * 4, stream);

    sniff_kernel<<<1, 64, 0, stream>>>((const u32*)ei, (const u32*)x, flags);

    normx_kernel<<<(NN * MM + 255) / 256, 256, 0, stream>>>(x, xf, NN * MM, flags);
    norm_weights_kernel<<<(WTOT + 255) / 256, 256, 0, stream>>>(
        d_in[2], d_in[3], d_in[4], d_in[5], d_in[6], d_in[7], d_in[8], d_in[9],
        d_in[10], d_in[11], d_in[12], d_in[13], d_in[14], d_in[15], d_in[16], d_in[17],
        wpk, flags);

    hist_kernel<<<(ETOT + 255) / 256, 256, 0, stream>>>(ei, flags, deg);
    scan_a<<<98, 256, 0, stream>>>(deg, offs, bsum);
    scan_b<<<1, 128, 0, stream>>>(bsum, bsumx, 98);
    scan_c<<<98, 256, 0, stream>>>(offs, bsumx, cursor);
    scatter_kernel<<<(ETOT + 255) / 256, 256, 0, stream>>>(ei, flags, cursor, srcs);

    const int GB = (NN + 127) / 128;  // 782

    // proj: h0 = xf @ Wp + bp
    gemm_kernel<<<GB, 256, 0, stream>>>(xf, wpk + OWp, wpk + Obp, h0, NN, MM, HID, 0, flags);

    // layer 1
    gemm_kernel<<<GB, 256, 0, stream>>>(h0, wpk + OW1l, nullptr, hl, NN, HID, HID, 0, flags);
    gemm_kernel<<<GB, 256, 0, stream>>>(h0, wpk + OW1r, nullptr, hr, NN, HID, HID, 0, flags);
    gat_agg_kernel<<<NN / 4, 256, 0, stream>>>(hl, hr, h0, wpk + Oatt1, wpk + Ob1,
                                               wpk + Og1, wpk + Obe1, offs, srcs, h1);

    // layer 2
    gemm_kernel<<<GB, 256, 0, stream>>>(h1, wpk + OW2l, nullptr, hl, NN, HID, HID, 0, flags);
    gemm_kernel<<<GB, 256, 0, stream>>>(h1, wpk + OW2r, nullptr, hr, NN, HID, HID, 0, flags);
    gat_agg_kernel<<<NN / 4, 256, 0, stream>>>(hl, hr, h1, wpk + Oatt2, wpk + Ob2,
                                               wpk + Og2, wpk + Obe2, offs, srcs, h0);

    // final: out = h0 @ Wo + bo (dtype per flags)
    gemm_kernel<<<GB, 256, 0, stream>>>(h0, wpk + OWo, wpk + Obo, d_out, NN, HID, LAT, 1, flags);
}

// Round 3
// 726.197 us; speedup vs baseline: 1.4159x; 1.4159x over previous
//
#include <hip/hip_runtime.h>
#include <hip/hip_bf16.h>
#include <math.h>

#define NN   100000
#define EE   1600000
#define ETOT 1700000   // EE + NN self loops
#define MM   40
#define HID  128
#define LAT  64

typedef unsigned short u16;
typedef unsigned int   u32;

typedef __attribute__((ext_vector_type(8))) short bf16x8;
typedef __attribute__((ext_vector_type(4))) float f32x4;

__device__ __forceinline__ float bf2f(u16 a) {
    return __uint_as_float(((u32)a) << 16);
}
__device__ __forceinline__ u16 f2bf(float f) {
    u32 u = __float_as_uint(f);
    u32 r = (u + 0x7fffu + ((u >> 16) & 1u)) >> 16;
    return (u16)r;
}

// f32 vector pack offsets (floats)
#define Vbp   0
#define Vatt1 128
#define Vb1   256
#define Vg1   384
#define Vbe1  512
#define Vatt2 640
#define Vb2   768
#define Vg2   896
#define Vbe2  1024
#define Vbo   1152
#define VTOT  1216

// bf16 transposed weight pack offsets (u16 elements)
#define BWp   0        // [128][64]  (K=40 zero-padded to 64)
#define BW1l  8192     // [128][128]
#define BW1r  24576
#define BW2l  40960
#define BW2r  57344
#define BWo   73728    // [64][128], padded to 128 rows (zeros) for wy=1 waves
#define BTOT  90112

// ---------------- dtype sniff ----------------
// flags[0] = 1 if edge_index is int64; flags[1] = 1 if float inputs are bf16
__global__ void sniff_kernel(const u32* __restrict__ ei_raw, const u32* __restrict__ x_raw,
                             int* __restrict__ flags) {
    if (threadIdx.x != 0 || blockIdx.x != 0) return;
    int allz = 1;
    for (int i = 1; i < 256; i += 2) allz &= (ei_raw[i] == 0u);   // int64 high words
    flags[0] = allz;
    int bf_like = 0;
    for (int i = 0; i < 64; i++) {
        u16 lo = (u16)(x_raw[i] & 0xffffu);
        int e = (lo >> 7) & 0xFF;               // bf16 exponent field of the low halfword
        if (e >= 118 && e <= 133) bf_like++;    // N(0,1)-plausible magnitude
    }
    flags[1] = (bf_like >= 48) ? 1 : 0;
}

// ---------------- normalize x -> bf16 [N,40] ----------------
__global__ void normx_kernel(const void* __restrict__ in, u16* __restrict__ out, int n,
                             const int* __restrict__ flags) {
    int i = blockIdx.x * 256 + threadIdx.x;
    if (i >= n) return;
    out[i] = flags[1] ? ((const u16*)in)[i] : f2bf(((const float*)in)[i]);
}

// ---------------- pack small vectors to f32 ----------------
__global__ void norm_vec_kernel(
    const void* p0, const void* p1, const void* p2, const void* p3, const void* p4,
    const void* p5, const void* p6, const void* p7, const void* p8, const void* p9,
    float* __restrict__ out, const int* __restrict__ flags)
{
    int i = blockIdx.x * 256 + threadIdx.x;
    if (i >= VTOT) return;
    const int offs[11] = {Vbp, Vatt1, Vb1, Vg1, Vbe1, Vatt2, Vb2, Vg2, Vbe2, Vbo, VTOT};
    const void* ps[10] = {p0,p1,p2,p3,p4,p5,p6,p7,p8,p9};
    int s = 0;
#pragma unroll
    for (int k = 1; k < 10; k++) s += (i >= offs[k]) ? 1 : 0;
    int j = i - offs[s];
    const void* p = ps[s];
    out[i] = flags[1] ? bf2f(((const u16*)p)[j]) : ((const float*)p)[j];
}

// ---------------- transpose weights to bf16 Wt[n][k] (zero k-pad) ----------------
__global__ void norm_wt_kernel(
    const void* w0, const void* w1, const void* w2, const void* w3, const void* w4,
    const void* w5, u16* __restrict__ out, const int* __restrict__ flags)
{
    int i = blockIdx.x * 256 + threadIdx.x;
    if (i >= BTOT) return;
    // seg: {off, K, Nc, Kp}
    const int offs[7] = {BWp, BW1l, BW1r, BW2l, BW2r, BWo, BTOT};
    const int Ks[6]   = {40, 128, 128, 128, 128, 128};
    const int Ncs[6]  = {128, 128, 128, 128, 128, 64};
    const int Kps[6]  = {64, 128, 128, 128, 128, 128};
    const void* ps[6] = {w0,w1,w2,w3,w4,w5};
    int s = 0;
#pragma unroll
    for (int k = 1; k < 6; k++) s += (i >= offs[k]) ? 1 : 0;
    int j = i - offs[s];
    int Kp = Kps[s];
    int n = j / Kp, k = j % Kp;
    u16 v = 0;
    if (k < Ks[s] && n < Ncs[s]) {
        const void* p = ps[s];
        int src = k * Ncs[s] + n;
        v = flags[1] ? ((const u16*)p)[src] : f2bf(((const float*)p)[src]);
    }
    out[i] = v;
}

// ---------------- CSR build ----------------
__global__ void hist_kernel(const int* __restrict__ ei, const int* __restrict__ flags,
                            int* __restrict__ deg) {
    int e = blockIdx.x * 256 + threadIdx.x;
    if (e >= ETOT) return;
    int dst;
    if (e < EE) {
        int idx = EE + e;
        dst = flags[0] ? ei[2 * idx] : ei[idx];
    } else {
        dst = e - EE;
    }
    atomicAdd(&deg[dst], 1);
}

__global__ void scan_a(const int* __restrict__ deg, int* __restrict__ offs, int* __restrict__ bsum) {
    __shared__ int sc[256];
    int t = threadIdx.x;
    int base = blockIdx.x * 1024 + t * 4;
    int e[4];
#pragma unroll
    for (int j = 0; j < 4; j++) { int i = base + j; e[j] = (i < NN) ? deg[i] : 0; }
    int tsum = e[0] + e[1] + e[2] + e[3];
    sc[t] = tsum; __syncthreads();
    for (int d = 1; d < 256; d <<= 1) {
        int v = (t >= d) ? sc[t - d] : 0;
        __syncthreads();
        sc[t] += v;
        __syncthreads();
    }
    int run = (t == 0) ? 0 : sc[t - 1];
#pragma unroll
    for (int j = 0; j < 4; j++) { int i = base + j; if (i < NN) offs[i] = run; run += e[j]; }
    if (t == 255) bsum[blockIdx.x] = sc[255];
}

__global__ void scan_b(const int* __restrict__ bsum, int* __restrict__ bsumx, int nb) {
    __shared__ int sc[128];
    int t = threadIdx.x;
    sc[t] = (t < nb) ? bsum[t] : 0; __syncthreads();
    for (int d = 1; d < 128; d <<= 1) {
        int v = (t >= d) ? sc[t - d] : 0;
        __syncthreads();
        sc[t] += v;
        __syncthreads();
    }
    bsumx[t] = (t == 0) ? 0 : sc[t - 1];
}

__global__ void scan_c(int* __restrict__ offs, const int* __restrict__ bsumx, int* __restrict__ cursor) {
    int t = threadIdx.x, b = blockIdx.x;
    int add = bsumx[b];
    int base = b * 1024 + t * 4;
#pragma unroll
    for (int j = 0; j < 4; j++) {
        int i = base + j;
        if (i < NN) { int v = offs[i] + add; offs[i] = v; cursor[i] = v; }
    }
    if (b == 0 && t == 0) offs[NN] = ETOT;
}

__global__ void scatter_kernel(const int* __restrict__ ei, const int* __restrict__ flags,
                               int* __restrict__ cursor, int* __restrict__ srcs) {
    int e = blockIdx.x * 256 + threadIdx.x;
    if (e >= ETOT) return;
    int src, dst;
    if (e < EE) {
        src = flags[0] ? ei[2 * e] : ei[e];
        int idx = EE + e;
        dst = flags[0] ? ei[2 * idx] : ei[idx];
    } else {
        src = e - EE; dst = src;
    }
    int pos = atomicAdd(&cursor[dst], 1);
    srcs[pos] = src;
}

// ---------------- MFMA GEMM: out[r,c] = sum_k A[r,k] * W[k,c] + bias[c] ----------------
// A: bf16 [>=nrows(+pad)][lda]; Bt: bf16 [ncols(padded)][ldb] with Bt[n][k] = W[k][n].
// Block: 256 thr = 4 waves (2x2), covers 128 rows x 128 cols. K = ksteps*32, fully unrolled-ish.
// mode: bit0 = write outF (f32), bit1 = write outB (bf16); mode<0: runtime flags[1]? bf16 : f32.
__global__ __launch_bounds__(256) void mfma_gemm(
    const u16* __restrict__ A, int lda,
    const u16* __restrict__ Bt, int ldb,
    const float* __restrict__ bias,
    int nrows, int ksteps, int ncols,
    float* __restrict__ outF, u16* __restrict__ outB, int ldo,
    int mode, const int* __restrict__ flags)
{
    int lane = threadIdx.x & 63;
    int wv = threadIdx.x >> 6;
    int wx = wv & 1, wy = wv >> 1;
    int l16 = lane & 15, quad = lane >> 4;
    int r0 = blockIdx.x * 128 + wx * 64;
    int n0 = wy * 64;

    f32x4 acc[4][4];
#pragma unroll
    for (int m = 0; m < 4; m++)
#pragma unroll
        for (int n = 0; n < 4; n++) acc[m][n] = (f32x4){0.f, 0.f, 0.f, 0.f};

    const u16* Ap = A + (size_t)(r0 + l16) * lda + quad * 8;
    const u16* Bp = Bt + (size_t)(n0 + l16) * ldb + quad * 8;

    for (int k = 0; k < ksteps; ++k) {
        bf16x8 af[4], bfr[4];
#pragma unroll
        for (int m = 0; m < 4; m++)
            af[m] = *(const bf16x8*)(Ap + (size_t)m * 16 * lda + k * 32);
#pragma unroll
        for (int n = 0; n < 4; n++)
            bfr[n] = *(const bf16x8*)(Bp + (size_t)n * 16 * ldb + k * 32);
#pragma unroll
        for (int m = 0; m < 4; m++)
#pragma unroll
            for (int n = 0; n < 4; n++)
                acc[m][n] = __builtin_amdgcn_mfma_f32_16x16x32_bf16(af[m], bfr[n], acc[m][n], 0, 0, 0);
    }

    int mk = mode;
    if (mk < 0) mk = flags[1] ? 2 : 1;

#pragma unroll
    for (int m = 0; m < 4; m++) {
#pragma unroll
        for (int n = 0; n < 4; n++) {
            int col = n0 + n * 16 + l16;
            float bb = (bias != nullptr && col < ncols) ? bias[col] : 0.f;
#pragma unroll
            for (int reg = 0; reg < 4; reg++) {
                int row = r0 + m * 16 + quad * 4 + reg;
                if (row < nrows && col < ncols) {
                    float v = acc[m][n][reg] + bb;
                    if (mk & 1) outF[(size_t)row * ldo + col] = v;
                    if (mk & 2) outB[(size_t)row * ldo + col] = f2bf(v);
                }
            }
        }
    }
}

// ---------------- fused GATv2 agg + bias + GELU + residual + LayerNorm ----------------
// one wave per dst node; 4 edges in flight (group g = lane>>4), lane r = lane&15 owns ch r*8..r*8+7
__global__ __launch_bounds__(256) void gat_agg_kernel(
    const u16* __restrict__ hl, const u16* __restrict__ hr, const float* __restrict__ hres,
    const float* __restrict__ att, const float* __restrict__ bias,
    const float* __restrict__ gamma, const float* __restrict__ beta,
    const int* __restrict__ offs, const int* __restrict__ srcs,
    float* __restrict__ out, u16* __restrict__ outb)
{
    int dst  = (blockIdx.x * 256 + threadIdx.x) >> 6;
    int lane = threadIdx.x & 63;
    int g = lane >> 4;
    int r = lane & 15;
    int c0 = r * 8;

    int start = offs[dst], end = offs[dst + 1];

    // dst-side projection (bf16) and attention vector (f32), 8 ch per lane
    float hrv[8], av[8];
    {
        uint4 q = *(const uint4*)(hr + ((size_t)dst << 7) + c0);
        hrv[0] = __uint_as_float(q.x << 16); hrv[1] = __uint_as_float(q.x & 0xffff0000u);
        hrv[2] = __uint_as_float(q.y << 16); hrv[3] = __uint_as_float(q.y & 0xffff0000u);
        hrv[4] = __uint_as_float(q.z << 16); hrv[5] = __uint_as_float(q.z & 0xffff0000u);
        hrv[6] = __uint_as_float(q.w << 16); hrv[7] = __uint_as_float(q.w & 0xffff0000u);
        float4 a0 = *(const float4*)&att[c0];
        float4 a1 = *(const float4*)&att[c0 + 4];
        av[0]=a0.x; av[1]=a0.y; av[2]=a0.z; av[3]=a0.w;
        av[4]=a1.x; av[5]=a1.y; av[6]=a1.z; av[7]=a1.w;
    }

    float acc[8] = {0,0,0,0,0,0,0,0};
    float s = 0.f;

    int iters = (end - start + 3) >> 2;
    for (int j = 0; j < iters; ++j) {
        int e = start + j * 4 + g;
        bool valid = e < end;
        int src = srcs[valid ? e : (end - 1)];
        uint4 q = *(const uint4*)(hl + ((size_t)src << 7) + c0);
        float h[8];
        h[0] = __uint_as_float(q.x << 16); h[1] = __uint_as_float(q.x & 0xffff0000u);
        h[2] = __uint_as_float(q.y << 16); h[3] = __uint_as_float(q.y & 0xffff0000u);
        h[4] = __uint_as_float(q.z << 16); h[5] = __uint_as_float(q.z & 0xffff0000u);
        h[6] = __uint_as_float(q.w << 16); h[7] = __uint_as_float(q.w & 0xffff0000u);
        float p = 0.f;
#pragma unroll
        for (int k = 0; k < 8; k++) {
            float z = h[k] + hrv[k];
            float lz = fmaxf(z, 0.2f * z);
            p = fmaf(av[k], lz, p);
        }
        // head = ch/32 = r/4 -> reduce over the 4 lanes r^{1,2} (same head)
        p += __shfl_xor(p, 1);
        p += __shfl_xor(p, 2);
        // logits bounded (|logit| < ~4): exp without max-subtraction is exact-safe in f32
        float w = valid ? __expf(p) : 0.f;
        s += w;
#pragma unroll
        for (int k = 0; k < 8; k++) acc[k] = fmaf(w, h[k], acc[k]);
    }

    // merge the 4 edge-groups (lanes differing in bits 4-5)
#pragma unroll
    for (int off = 16; off < 64; off <<= 1) {
        s += __shfl_xor(s, off);
#pragma unroll
        for (int k = 0; k < 8; k++) acc[k] += __shfl_xor(acc[k], off);
    }

    float inv = 1.f / s;
    float v[8];
    {
        float4 b0 = *(const float4*)&bias[c0];
        float4 b1 = *(const float4*)&bias[c0 + 4];
        float bb[8] = {b0.x,b0.y,b0.z,b0.w,b1.x,b1.y,b1.z,b1.w};
        float4 r0v = *(const float4*)&hres[((size_t)dst << 7) + c0];
        float4 r1v = *(const float4*)&hres[((size_t)dst << 7) + c0 + 4];
        float rr[8] = {r0v.x,r0v.y,r0v.z,r0v.w,r1v.x,r1v.y,r1v.z,r1v.w};
#pragma unroll
        for (int k = 0; k < 8; k++) {
            float t = acc[k] * inv + bb[k];
            t = 0.5f * t * (1.f + erff(t * 0.70710678118654752f));  // exact GELU
            v[k] = t + rr[k];
        }
    }

    // LayerNorm over 128 ch: partials over 8 ch, reduce across 16 lanes (r bits)
    float s1 = 0.f, s2 = 0.f;
#pragma unroll
    for (int k = 0; k < 8; k++) { s1 += v[k]; s2 = fmaf(v[k], v[k], s2); }
#pragma unroll
    for (int off = 1; off < 16; off <<= 1) {
        s1 += __shfl_xor(s1, off);
        s2 += __shfl_xor(s2, off);
    }
    float mu  = s1 * (1.f / 128.f);
    float var = s2 * (1.f / 128.f) - mu * mu;
    float rstd = rsqrtf(var + 1e-5f);

    if (g == 0) {
        float4 g0 = *(const float4*)&gamma[c0];
        float4 g1 = *(const float4*)&gamma[c0 + 4];
        float4 be0 = *(const float4*)&beta[c0];
        float4 be1 = *(const float4*)&beta[c0 + 4];
        float gg[8] = {g0.x,g0.y,g0.z,g0.w,g1.x,g1.y,g1.z,g1.w};
        float eb[8] = {be0.x,be0.y,be0.z,be0.w,be1.x,be1.y,be1.z,be1.w};
        float o[8];
#pragma unroll
        for (int k = 0; k < 8; k++) o[k] = (v[k] - mu) * rstd * gg[k] + eb[k];
        *(float4*)&out[((size_t)dst << 7) + c0]     = make_float4(o[0], o[1], o[2], o[3]);
        *(float4*)&out[((size_t)dst << 7) + c0 + 4] = make_float4(o[4], o[5], o[6], o[7]);
        uint4 pk;
        pk.x = (u32)f2bf(o[0]) | ((u32)f2bf(o[1]) << 16);
        pk.y = (u32)f2bf(o[2]) | ((u32)f2bf(o[3]) << 16);
        pk.z = (u32)f2bf(o[4]) | ((u32)f2bf(o[5]) << 16);
        pk.w = (u32)f2bf(o[6]) | ((u32)f2bf(o[7]) << 16);
        *(uint4*)(outb + ((size_t)dst << 7) + c0) = pk;
    }
}

// ---------------- launch ----------------
extern "C" void kernel_launch(void* const* d_in, const int* in_sizes, int n_in,
                              void* d_out, int out_size, void* d_ws, size_t ws_size,
                              hipStream_t stream) {
    const void* x  = d_in[0];
    const int*  ei = (const int*)d_in[1];

    char* ws = (char*)d_ws;
    size_t off = 0;
    auto alloc = [&](size_t bytes) -> void* {
        void* p = ws + off;
        off = (off + bytes + 511) & ~(size_t)511;
        return p;
    };
    u16*   xb     = (u16*)  alloc(((size_t)NN * MM + 8192) * 2);     // bf16 x (+OOB pad)
    float* wv     = (float*)alloc((size_t)VTOT * 4);
    u16*   wbf    = (u16*)  alloc((size_t)BTOT * 2);
    float* h0     = (float*)alloc((size_t)(NN + 64) * HID * 4);
    u16*   h0b    = (u16*)  alloc((size_t)(NN + 64) * HID * 2);
    float* h1     = (float*)alloc((size_t)(NN + 64) * HID * 4);
    u16*   h1b    = (u16*)  alloc((size_t)(NN + 64) * HID * 2);
    u16*   hlb    = (u16*)  alloc((size_t)NN * HID * 2);
    u16*   hrb    = (u16*)  alloc((size_t)NN * HID * 2);
    int*   offs   = (int*)  alloc((size_t)(NN + 1) * 4);
    int*   cursor = (int*)  alloc((size_t)NN * 4);
    int*   deg    = (int*)  alloc((size_t)NN * 4);
    int*   bsum   = (int*)  alloc(512);
    int*   bsumx  = (int*)  alloc(512);
    int*   flags  = (int*)  alloc(512);
    int*   srcs   = (int*)  alloc((size_t)ETOT * 4);

    hipMemsetAsync(deg, 0, (size_t)NN * 4, stream);

    sniff_kernel<<<1, 64, 0, stream>>>((const u32*)ei, (const u32*)x, flags);

    normx_kernel<<<(NN * MM + 255) / 256, 256, 0, stream>>>(x, xb, NN * MM, flags);
    norm_vec_kernel<<<(VTOT + 255) / 256, 256, 0, stream>>>(
        d_in[3], d_in[6], d_in[7], d_in[12], d_in[13], d_in[10], d_in[11], d_in[14], d_in[15], d_in[17],
        wv, flags);
    norm_wt_kernel<<<(BTOT + 255) / 256, 256, 0, stream>>>(
        d_in[2], d_in[4], d_in[5], d_in[8], d_in[9], d_in[16], wbf, flags);

    hist_kernel<<<(ETOT + 255) / 256, 256, 0, stream>>>(ei, flags, deg);
    scan_a<<<98, 256, 0, stream>>>(deg, offs, bsum);
    scan_b<<<1, 128, 0, stream>>>(bsum, bsumx, 98);
    scan_c<<<98, 256, 0, stream>>>(offs, bsumx, cursor);
    scatter_kernel<<<(ETOT + 255) / 256, 256, 0, stream>>>(ei, flags, cursor, srcs);

    const int GB = (NN + 127) / 128;  // 782

    // proj: h0(f32)+h0b(bf16) = x @ Wp + bp   (K=40 padded to 64)
    mfma_gemm<<<GB, 256, 0, stream>>>(xb, MM, wbf + BWp, 64, wv + Vbp,
                                      NN, 2, HID, h0, h0b, HID, 3, flags);

    // layer 1: hl = h0 @ W1l ; hr = h0 @ W1r  (bf16 out only)
    mfma_gemm<<<GB, 256, 0, stream>>>(h0b, HID, wbf + BW1l, HID, nullptr,
                                      NN, 4, HID, nullptr, hlb, HID, 2, flags);
    mfma_gemm<<<GB, 256, 0, stream>>>(h0b, HID, wbf + BW1r, HID, nullptr,
                                      NN, 4, HID, nullptr, hrb, HID, 2, flags);
    gat_agg_kernel<<<NN / 4, 256, 0, stream>>>(hlb, hrb, h0, wv + Vatt1, wv + Vb1,
                                               wv + Vg1, wv + Vbe1, offs, srcs, h1, h1b);

    // layer 2
    mfma_gemm<<<GB, 256, 0, stream>>>(h1b, HID, wbf + BW2l, HID, nullptr,
                                      NN, 4, HID, nullptr, hlb, HID, 2, flags);
    mfma_gemm<<<GB, 256, 0, stream>>>(h1b, HID, wbf + BW2r, HID, nullptr,
                                      NN, 4, HID, nullptr, hrb, HID, 2, flags);
    gat_agg_kernel<<<NN / 4, 256, 0, stream>>>(hlb, hrb, h1, wv + Vatt2, wv + Vb2,
                                               wv + Vg2, wv + Vbe2, offs, srcs, h0, h0b);

    // final: out = h @ Wo + bo (dtype per flags)
    mfma_gemm<<<GB, 256, 0, stream>>>(h0b, HID, wbf + BWo, HID, wv + Vbo,
                                      NN, 4, LAT, (float*)d_out, (u16*)d_out, LAT, -1, flags);
}

// Round 4
// 572.449 us; speedup vs baseline: 1.7962x; 1.2686x over previous
//
#include <hip/hip_runtime.h>
#include <hip/hip_bf16.h>
#include <math.h>

#define NN   100000
#define EE   1600000
#define ETOT 1700000   // EE + NN self loops
#define MM   40
#define HID  128
#define LAT  64
#define NB   391       // ceil(NN/256) buckets of 256 nodes
#define CHUNK 4096     // edges per bin_pass block

typedef unsigned short u16;
typedef unsigned int   u32;
typedef unsigned long long u64;

typedef __attribute__((ext_vector_type(8))) short bf16x8;
typedef __attribute__((ext_vector_type(4))) float f32x4;

__device__ __forceinline__ float bf2f(u16 a) {
    return __uint_as_float(((u32)a) << 16);
}
__device__ __forceinline__ u16 f2bf(float f) {
    u32 u = __float_as_uint(f);
    u32 r = (u + 0x7fffu + ((u >> 16) & 1u)) >> 16;
    return (u16)r;
}

// f32 vector pack offsets (floats)
#define Vbp   0
#define Vatt1 128
#define Vb1   256
#define Vg1   384
#define Vbe1  512
#define Vatt2 640
#define Vb2   768
#define Vg2   896
#define Vbe2  1024
#define Vbo   1152
#define VTOT  1216

// bf16 transposed weight pack offsets (u16 elements)
#define BWp   0        // [128][64]  (K=40 zero-padded to 64)
#define BW1l  8192     // [128][128]
#define BW1r  24576    // = BW1l + 128*128 (adjacent: gridDim.y=2 trick relies on this)
#define BW2l  40960
#define BW2r  57344    // = BW2l + 128*128
#define BWo   73728    // [64][128], padded to 128 rows (zeros)
#define BTOT  90112

// ---------------- dtype sniff ----------------
// flags[0] = 1 if edge_index is int64; flags[1] = 1 if float inputs are bf16
__global__ void sniff_kernel(const u32* __restrict__ ei_raw, const u32* __restrict__ x_raw,
                             int* __restrict__ flags) {
    if (threadIdx.x != 0 || blockIdx.x != 0) return;
    int allz = 1;
    for (int i = 1; i < 256; i += 2) allz &= (ei_raw[i] == 0u);   // int64 high words
    flags[0] = allz;
    int bf_like = 0;
    for (int i = 0; i < 64; i++) {
        u16 lo = (u16)(x_raw[i] & 0xffffu);
        int e = (lo >> 7) & 0xFF;
        if (e >= 118 && e <= 133) bf_like++;
    }
    flags[1] = (bf_like >= 48) ? 1 : 0;
}

__device__ __forceinline__ void edge_decode(const int* __restrict__ ei, int is64, int e,
                                            int& src, int& dst) {
    if (e < EE) {
        src = is64 ? ei[2 * e] : ei[e];
        int idx = EE + e;
        dst = is64 ? ei[2 * idx] : ei[idx];
    } else {
        src = e - EE; dst = src;
    }
}

// ---------------- normalize x -> bf16 ----------------
__global__ void normx_kernel(const void* __restrict__ in, u16* __restrict__ out, int n,
                             const int* __restrict__ flags) {
    int i = blockIdx.x * 256 + threadIdx.x;
    if (i >= n) return;
    out[i] = flags[1] ? ((const u16*)in)[i] : f2bf(((const float*)in)[i]);
}

// ---------------- pack small vectors to f32 ----------------
__global__ void norm_vec_kernel(
    const void* p0, const void* p1, const void* p2, const void* p3, const void* p4,
    const void* p5, const void* p6, const void* p7, const void* p8, const void* p9,
    float* __restrict__ out, const int* __restrict__ flags)
{
    int i = blockIdx.x * 256 + threadIdx.x;
    if (i >= VTOT) return;
    const int offs[11] = {Vbp, Vatt1, Vb1, Vg1, Vbe1, Vatt2, Vb2, Vg2, Vbe2, Vbo, VTOT};
    const void* ps[10] = {p0,p1,p2,p3,p4,p5,p6,p7,p8,p9};
    int s = 0;
#pragma unroll
    for (int k = 1; k < 10; k++) s += (i >= offs[k]) ? 1 : 0;
    int j = i - offs[s];
    const void* p = ps[s];
    out[i] = flags[1] ? bf2f(((const u16*)p)[j]) : ((const float*)p)[j];
}

// ---------------- transpose weights to bf16 Wt[n][k] (zero k-pad) ----------------
__global__ void norm_wt_kernel(
    const void* w0, const void* w1, const void* w2, const void* w3, const void* w4,
    const void* w5, u16* __restrict__ out, const int* __restrict__ flags)
{
    int i = blockIdx.x * 256 + threadIdx.x;
    if (i >= BTOT) return;
    const int offs[7] = {BWp, BW1l, BW1r, BW2l, BW2r, BWo, BTOT};
    const int Ks[6]   = {40, 128, 128, 128, 128, 128};
    const int Ncs[6]  = {128, 128, 128, 128, 128, 64};
    const int Kps[6]  = {64, 128, 128, 128, 128, 128};
    const void* ps[6] = {w0,w1,w2,w3,w4,w5};
    int s = 0;
#pragma unroll
    for (int k = 1; k < 6; k++) s += (i >= offs[k]) ? 1 : 0;
    int j = i - offs[s];
    int Kp = Kps[s];
    int n = j / Kp, k = j % Kp;
    u16 v = 0;
    if (k < Ks[s] && n < Ncs[s]) {
        const void* p = ps[s];
        int src = k * Ncs[s] + n;
        v = flags[1] ? ((const u16*)p)[src] : f2bf(((const float*)p)[src]);
    }
    out[i] = v;
}

// ---------------- CSR build: 2-pass LDS-binned counting sort ----------------

// Pass A: global bucket histogram (bucket = dst>>8)
__global__ __launch_bounds__(256) void bucket_hist_kernel(
    const int* __restrict__ ei, const int* __restrict__ flags, u32* __restrict__ gbucket)
{
    __shared__ u32 h[512];
    int t = threadIdx.x;
    h[t] = 0; h[t + 256] = 0;
    __syncthreads();
    int is64 = flags[0];
    int base = blockIdx.x * CHUNK;
#pragma unroll
    for (int j = 0; j < CHUNK / 256; j++) {
        int e = base + j * 256 + t;
        if (e < ETOT) {
            int src, dst;
            edge_decode(ei, is64, e, src, dst);
            atomicAdd(&h[dst >> 8], 1u);
        }
    }
    __syncthreads();
    if (h[t])       atomicAdd(&gbucket[t], h[t]);
    if (h[t + 256]) atomicAdd(&gbucket[t + 256], h[t + 256]);
}

// Pass B: exclusive scan of 391 bucket counts -> base + cursor
__global__ __launch_bounds__(256) void bucket_scan_kernel(
    const u32* __restrict__ gbucket, u32* __restrict__ bbase, u32* __restrict__ bcursor)
{
    __shared__ u32 ts[256];
    int t = threadIdx.x;
    u32 s0 = (2 * t     < NB) ? gbucket[2 * t]     : 0;
    u32 s1 = (2 * t + 1 < NB) ? gbucket[2 * t + 1] : 0;
    u32 tsum = s0 + s1;
    ts[t] = tsum; __syncthreads();
    for (int d = 1; d < 256; d <<= 1) {
        u32 v = (t >= d) ? ts[t - d] : 0;
        __syncthreads();
        ts[t] += v;
        __syncthreads();
    }
    u32 excl = ts[t] - tsum;
    bbase[2 * t] = excl;       bcursor[2 * t] = excl;
    bbase[2 * t + 1] = excl + s0; bcursor[2 * t + 1] = excl + s0;
    if (t == 255) bbase[512 - 1] = 0;   // unused tail
    if (2 * t == NB - 1 || 2 * t + 1 == NB - 1) bbase[NB] = ETOT;
}

// Pass C: bin edges into bucket regions (coalesced staged writes)
__global__ __launch_bounds__(256) void bin_pass_kernel(
    const int* __restrict__ ei, const int* __restrict__ flags,
    u32* __restrict__ bcursor, u64* __restrict__ pairs)
{
    __shared__ u32 bh[512];    // per-block bucket hist
    __shared__ u32 boff[512];  // exclusive offsets within chunk
    __shared__ u32 bbs[512];   // reserved global base per bucket
    __shared__ u32 bcur[512];
    __shared__ u64 stage[CHUNK];
    __shared__ u32 ts[256];

    int t = threadIdx.x;
    bh[t] = 0; bh[t + 256] = 0;
    __syncthreads();
    int is64 = flags[0];
    int base = blockIdx.x * CHUNK;
    int chunk_n = ETOT - base; if (chunk_n > CHUNK) chunk_n = CHUNK;

#pragma unroll
    for (int j = 0; j < CHUNK / 256; j++) {
        int e = base + j * 256 + t;
        if (e < ETOT) {
            int src, dst;
            edge_decode(ei, is64, e, src, dst);
            atomicAdd(&bh[dst >> 8], 1u);
        }
    }
    __syncthreads();
    // scan 512 (2 per thread)
    u32 s0 = bh[2 * t], s1 = bh[2 * t + 1];
    u32 tsum = s0 + s1;
    ts[t] = tsum; __syncthreads();
    for (int d = 1; d < 256; d <<= 1) {
        u32 v = (t >= d) ? ts[t - d] : 0;
        __syncthreads();
        ts[t] += v;
        __syncthreads();
    }
    u32 excl = ts[t] - tsum;
    boff[2 * t] = excl; boff[2 * t + 1] = excl + s0;
    bcur[2 * t] = excl; bcur[2 * t + 1] = excl + s0;
    __syncthreads();
    // reserve global ranges
    if (t < NB && bh[t]) bbs[t] = atomicAdd(&bcursor[t], bh[t]);
    if (t + 256 < NB && bh[t + 256]) bbs[t + 256] = atomicAdd(&bcursor[t + 256], bh[t + 256]);
    __syncthreads();
    // stage ordered by bucket
#pragma unroll
    for (int j = 0; j < CHUNK / 256; j++) {
        int e = base + j * 256 + t;
        if (e < ETOT) {
            int src, dst;
            edge_decode(ei, is64, e, src, dst);
            u32 pos = atomicAdd(&bcur[dst >> 8], 1u);
            stage[pos] = (u64)src | ((u64)dst << 32);
        }
    }
    __syncthreads();
    // coalesced write-out
    for (int i = t; i < chunk_n; i += 256) {
        u64 pr = stage[i];
        u32 b = (u32)(pr >> 32) >> 8;
        pairs[(size_t)bbs[b] + (i - boff[b])] = pr;
    }
}

// Pass D: per-bucket counting sort -> srcs + offs
__global__ __launch_bounds__(256) void sort_pass_kernel(
    const u64* __restrict__ pairs, const u32* __restrict__ bbase,
    int* __restrict__ srcs, int* __restrict__ offs)
{
    __shared__ u32 nh[256];
    __shared__ u32 ns[256];
    __shared__ u32 ncur[256];
    int t = threadIdx.x;
    int b = blockIdx.x;
    u32 beg = bbase[b], endp = bbase[b + 1];
    nh[t] = 0;
    __syncthreads();
    for (u32 i = beg + t; i < endp; i += 256) {
        u32 dst = (u32)(pairs[i] >> 32);
        atomicAdd(&nh[dst & 255], 1u);
    }
    __syncthreads();
    u32 cnt = nh[t];
    ns[t] = cnt; __syncthreads();
    for (int d = 1; d < 256; d <<= 1) {
        u32 v = (t >= d) ? ns[t - d] : 0;
        __syncthreads();
        ns[t] += v;
        __syncthreads();
    }
    u32 excl = ns[t] - cnt;
    int id = b * 256 + t;
    if (id <= NN) offs[id] = (int)(beg + excl);
    ncur[t] = excl;
    __syncthreads();
    for (u32 i = beg + t; i < endp; i += 256) {
        u64 pr = pairs[i];
        u32 loc = ((u32)(pr >> 32)) & 255;
        u32 p = atomicAdd(&ncur[loc], 1u);
        srcs[beg + p] = (int)(u32)pr;
    }
}

// ---------------- MFMA GEMM ----------------
// A: bf16 [rows][lda]; Bt: bf16 [cols][ldb], Bt[n][k]=W[k][n]. Block covers 128x128.
// gridDim.y selects a second 128-col weight panel (Bt += y*128*ldb) and outB2.
__global__ __launch_bounds__(256) void mfma_gemm(
    const u16* __restrict__ A, int lda,
    const u16* __restrict__ Bt, int ldb,
    const float* __restrict__ bias,
    int nrows, int ksteps, int ncols,
    float* __restrict__ outF, u16* __restrict__ outB, u16* __restrict__ outB2, int ldo,
    int mode, const int* __restrict__ flags)
{
    int lane = threadIdx.x & 63;
    int wv = threadIdx.x >> 6;
    int wx = wv & 1, wy = wv >> 1;
    int l16 = lane & 15, quad = lane >> 4;
    int r0 = blockIdx.x * 128 + wx * 64;
    int n0 = wy * 64;

    Bt += (size_t)blockIdx.y * 128 * ldb;
    if (blockIdx.y) outB = outB2;

    f32x4 acc[4][4];
#pragma unroll
    for (int m = 0; m < 4; m++)
#pragma unroll
        for (int n = 0; n < 4; n++) acc[m][n] = (f32x4){0.f, 0.f, 0.f, 0.f};

    const u16* Ap = A + (size_t)(r0 + l16) * lda + quad * 8;
    const u16* Bp = Bt + (size_t)(n0 + l16) * ldb + quad * 8;

    for (int k = 0; k < ksteps; ++k) {
        bf16x8 af[4], bfr[4];
#pragma unroll
        for (int m = 0; m < 4; m++)
            af[m] = *(const bf16x8*)(Ap + (size_t)m * 16 * lda + k * 32);
#pragma unroll
        for (int n = 0; n < 4; n++)
            bfr[n] = *(const bf16x8*)(Bp + (size_t)n * 16 * ldb + k * 32);
#pragma unroll
        for (int m = 0; m < 4; m++)
#pragma unroll
            for (int n = 0; n < 4; n++)
                acc[m][n] = __builtin_amdgcn_mfma_f32_16x16x32_bf16(af[m], bfr[n], acc[m][n], 0, 0, 0);
    }

    int mk = mode;
    if (mk < 0) mk = flags[1] ? 2 : 1;

#pragma unroll
    for (int m = 0; m < 4; m++) {
#pragma unroll
        for (int n = 0; n < 4; n++) {
            int col = n0 + n * 16 + l16;
            float bb = (bias != nullptr && col < ncols) ? bias[col] : 0.f;
#pragma unroll
            for (int reg = 0; reg < 4; reg++) {
                int row = r0 + m * 16 + quad * 4 + reg;
                if (row < nrows && col < ncols) {
                    float v = acc[m][n][reg] + bb;
                    if (mk & 1) outF[(size_t)row * ldo + col] = v;
                    if (mk & 2) outB[(size_t)row * ldo + col] = f2bf(v);
                }
            }
        }
    }
}

// ---------------- fused GATv2 agg + bias + GELU + residual + LayerNorm ----------------
__global__ __launch_bounds__(256) void gat_agg_kernel(
    const u16* __restrict__ hl, const u16* __restrict__ hr, const float* __restrict__ hres,
    const float* __restrict__ att, const float* __restrict__ bias,
    const float* __restrict__ gamma, const float* __restrict__ beta,
    const int* __restrict__ offs, const int* __restrict__ srcs,
    float* __restrict__ out, u16* __restrict__ outb)
{
    int dst  = (blockIdx.x * 256 + threadIdx.x) >> 6;
    int lane = threadIdx.x & 63;
    int g = lane >> 4;
    int r = lane & 15;
    int c0 = r * 8;

    int start = offs[dst], end = offs[dst + 1];

    float hrv[8], av[8];
    {
        uint4 q = *(const uint4*)(hr + ((size_t)dst << 7) + c0);
        hrv[0] = __uint_as_float(q.x << 16); hrv[1] = __uint_as_float(q.x & 0xffff0000u);
        hrv[2] = __uint_as_float(q.y << 16); hrv[3] = __uint_as_float(q.y & 0xffff0000u);
        hrv[4] = __uint_as_float(q.z << 16); hrv[5] = __uint_as_float(q.z & 0xffff0000u);
        hrv[6] = __uint_as_float(q.w << 16); hrv[7] = __uint_as_float(q.w & 0xffff0000u);
        float4 a0 = *(const float4*)&att[c0];
        float4 a1 = *(const float4*)&att[c0 + 4];
        av[0]=a0.x; av[1]=a0.y; av[2]=a0.z; av[3]=a0.w;
        av[4]=a1.x; av[5]=a1.y; av[6]=a1.z; av[7]=a1.w;
    }

    float acc[8] = {0,0,0,0,0,0,0,0};
    float s = 0.f;

    int iters = (end - start + 3) >> 2;
    for (int j = 0; j < iters; ++j) {
        int e = start + j * 4 + g;
        bool valid = e < end;
        int src = srcs[valid ? e : (end - 1)];
        uint4 q = *(const uint4*)(hl + ((size_t)src << 7) + c0);
        float h[8];
        h[0] = __uint_as_float(q.x << 16); h[1] = __uint_as_float(q.x & 0xffff0000u);
        h[2] = __uint_as_float(q.y << 16); h[3] = __uint_as_float(q.y & 0xffff0000u);
        h[4] = __uint_as_float(q.z << 16); h[5] = __uint_as_float(q.z & 0xffff0000u);
        h[6] = __uint_as_float(q.w << 16); h[7] = __uint_as_float(q.w & 0xffff0000u);
        float p = 0.f;
#pragma unroll
        for (int k = 0; k < 8; k++) {
            float z = h[k] + hrv[k];
            float lz = fmaxf(z, 0.2f * z);
            p = fmaf(av[k], lz, p);
        }
        p += __shfl_xor(p, 1);
        p += __shfl_xor(p, 2);
        float w = valid ? __expf(p) : 0.f;
        s += w;
#pragma unroll
        for (int k = 0; k < 8; k++) acc[k] = fmaf(w, h[k], acc[k]);
    }

#pragma unroll
    for (int off = 16; off < 64; off <<= 1) {
        s += __shfl_xor(s, off);
#pragma unroll
        for (int k = 0; k < 8; k++) acc[k] += __shfl_xor(acc[k], off);
    }

    float inv = 1.f / s;
    float v[8];
    {
        float4 b0 = *(const float4*)&bias[c0];
        float4 b1 = *(const float4*)&bias[c0 + 4];
        float bb[8] = {b0.x,b0.y,b0.z,b0.w,b1.x,b1.y,b1.z,b1.w};
        float4 r0v = *(const float4*)&hres[((size_t)dst << 7) + c0];
        float4 r1v = *(const float4*)&hres[((size_t)dst << 7) + c0 + 4];
        float rr[8] = {r0v.x,r0v.y,r0v.z,r0v.w,r1v.x,r1v.y,r1v.z,r1v.w};
#pragma unroll
        for (int k = 0; k < 8; k++) {
            float t = acc[k] * inv + bb[k];
            t = 0.5f * t * (1.f + erff(t * 0.70710678118654752f));
            v[k] = t + rr[k];
        }
    }

    float s1 = 0.f, s2 = 0.f;
#pragma unroll
    for (int k = 0; k < 8; k++) { s1 += v[k]; s2 = fmaf(v[k], v[k], s2); }
#pragma unroll
    for (int off = 1; off < 16; off <<= 1) {
        s1 += __shfl_xor(s1, off);
        s2 += __shfl_xor(s2, off);
    }
    float mu  = s1 * (1.f / 128.f);
    float var = s2 * (1.f / 128.f) - mu * mu;
    float rstd = rsqrtf(var + 1e-5f);

    if (g == 0) {
        float4 g0 = *(const float4*)&gamma[c0];
        float4 g1 = *(const float4*)&gamma[c0 + 4];
        float4 be0 = *(const float4*)&beta[c0];
        float4 be1 = *(const float4*)&beta[c0 + 4];
        float gg[8] = {g0.x,g0.y,g0.z,g0.w,g1.x,g1.y,g1.z,g1.w};
        float eb[8] = {be0.x,be0.y,be0.z,be0.w,be1.x,be1.y,be1.z,be1.w};
        float o[8];
#pragma unroll
        for (int k = 0; k < 8; k++) o[k] = (v[k] - mu) * rstd * gg[k] + eb[k];
        *(float4*)&out[((size_t)dst << 7) + c0]     = make_float4(o[0], o[1], o[2], o[3]);
        *(float4*)&out[((size_t)dst << 7) + c0 + 4] = make_float4(o[4], o[5], o[6], o[7]);
        uint4 pk;
        pk.x = (u32)f2bf(o[0]) | ((u32)f2bf(o[1]) << 16);
        pk.y = (u32)f2bf(o[2]) | ((u32)f2bf(o[3]) << 16);
        pk.z = (u32)f2bf(o[4]) | ((u32)f2bf(o[5]) << 16);
        pk.w = (u32)f2bf(o[6]) | ((u32)f2bf(o[7]) << 16);
        *(uint4*)(outb + ((size_t)dst << 7) + c0) = pk;
    }
}

// ---------------- launch ----------------
extern "C" void kernel_launch(void* const* d_in, const int* in_sizes, int n_in,
                              void* d_out, int out_size, void* d_ws, size_t ws_size,
                              hipStream_t stream) {
    const void* x  = d_in[0];
    const int*  ei = (const int*)d_in[1];

    char* ws = (char*)d_ws;
    size_t off = 0;
    auto alloc = [&](size_t bytes) -> void* {
        void* p = ws + off;
        off = (off + bytes + 511) & ~(size_t)511;
        return p;
    };
    u16*   xb      = (u16*)  alloc(((size_t)NN * MM + 8192) * 2);
    float* wv      = (float*)alloc((size_t)VTOT * 4);
    u16*   wbf     = (u16*)  alloc((size_t)BTOT * 2);
    float* h0      = (float*)alloc((size_t)(NN + 64) * HID * 4);
    u16*   h0b     = (u16*)  alloc((size_t)(NN + 64) * HID * 2);
    float* h1      = (float*)alloc((size_t)(NN + 64) * HID * 4);
    u16*   h1b     = (u16*)  alloc((size_t)(NN + 64) * HID * 2);
    u16*   hlb     = (u16*)  alloc((size_t)NN * HID * 2);
    u16*   hrb     = (u16*)  alloc((size_t)NN * HID * 2);
    int*   offs    = (int*)  alloc((size_t)(NN + 1) * 4);
    u32*   gbucket = (u32*)  alloc(512 * 4);
    u32*   bbase   = (u32*)  alloc(520 * 4);
    u32*   bcursor = (u32*)  alloc(520 * 4);
    int*   flags   = (int*)  alloc(512);
    int*   srcs    = (int*)  alloc((size_t)ETOT * 4);
    u64*   pairs   = (u64*)  alloc((size_t)ETOT * 8);

    hipMemsetAsync(gbucket, 0, 512 * 4, stream);

    sniff_kernel<<<1, 64, 0, stream>>>((const u32*)ei, (const u32*)x, flags);

    normx_kernel<<<(NN * MM + 255) / 256, 256, 0, stream>>>(x, xb, NN * MM, flags);
    norm_vec_kernel<<<(VTOT + 255) / 256, 256, 0, stream>>>(
        d_in[3], d_in[6], d_in[7], d_in[12], d_in[13], d_in[10], d_in[11], d_in[14], d_in[15], d_in[17],
        wv, flags);
    norm_wt_kernel<<<(BTOT + 255) / 256, 256, 0, stream>>>(
        d_in[2], d_in[4], d_in[5], d_in[8], d_in[9], d_in[16], wbf, flags);

    const int EB = (ETOT + CHUNK - 1) / CHUNK;  // 416
    bucket_hist_kernel<<<EB, 256, 0, stream>>>(ei, flags, gbucket);
    bucket_scan_kernel<<<1, 256, 0, stream>>>(gbucket, bbase, bcursor);
    bin_pass_kernel<<<EB, 256, 0, stream>>>(ei, flags, bcursor, pairs);
    sort_pass_kernel<<<NB, 256, 0, stream>>>(pairs, bbase, srcs, offs);

    const int GB = (NN + 127) / 128;  // 782

    // proj: h0(f32)+h0b(bf16) = x @ Wp + bp   (K=40 padded to 64)
    mfma_gemm<<<dim3(GB, 1), 256, 0, stream>>>(xb, MM, wbf + BWp, 64, wv + Vbp,
                                               NN, 2, HID, h0, h0b, nullptr, HID, 3, flags);

    // layer 1: hl/hr in one dispatch (gridDim.y picks W1l vs W1r panel)
    mfma_gemm<<<dim3(GB, 2), 256, 0, stream>>>(h0b, HID, wbf + BW1l, HID, nullptr,
                                               NN, 4, HID, nullptr, hlb, hrb, HID, 2, flags);
    gat_agg_kernel<<<NN / 4, 256, 0, stream>>>(hlb, hrb, h0, wv + Vatt1, wv + Vb1,
                                               wv + Vg1, wv + Vbe1, offs, srcs, h1, h1b);

    // layer 2
    mfma_gemm<<<dim3(GB, 2), 256, 0, stream>>>(h1b, HID, wbf + BW2l, HID, nullptr,
                                               NN, 4, HID, nullptr, hlb, hrb, HID, 2, flags);
    gat_agg_kernel<<<NN / 4, 256, 0, stream>>>(hlb, hrb, h1, wv + Vatt2, wv + Vb2,
                                               wv + Vg2, wv + Vbe2, offs, srcs, h0, h0b);

    // final: out = h @ Wo + bo (dtype per flags)
    mfma_gemm<<<dim3(GB, 1), 256, 0, stream>>>(h0b, HID, wbf + BWo, HID, wv + Vbo,
                                               NN, 4, LAT, (float*)d_out, (u16*)d_out, nullptr, LAT, -1, flags);
}

// Round 5
// 554.890 us; speedup vs baseline: 1.8530x; 1.0316x over previous
//
#include <hip/hip_runtime.h>
#include <hip/hip_bf16.h>
#include <math.h>

#define NN   100000
#define EE   1600000
#define ETOT 1700000   // EE + NN self loops
#define MM   40
#define HID  128
#define LAT  64
#define NB   391       // ceil(NN/256) buckets of 256 nodes
#define CHUNK 4096     // edges per bin_pass block

typedef unsigned short u16;
typedef unsigned int   u32;
typedef unsigned long long u64;

typedef __attribute__((ext_vector_type(8))) short bf16x8;
typedef __attribute__((ext_vector_type(4))) float f32x4;
typedef __attribute__((ext_vector_type(2))) float f32x2;

__device__ __forceinline__ float bf2f(u16 a) {
    return __uint_as_float(((u32)a) << 16);
}
__device__ __forceinline__ u16 f2bf(float f) {
    u32 u = __float_as_uint(f);
    u32 r = (u + 0x7fffu + ((u >> 16) & 1u)) >> 16;
    return (u16)r;
}
// unpack a bf16 pair (little-endian packed in u32) to two f32 (packed-math friendly)
__device__ __forceinline__ f32x2 unpk(u32 u) {
    f32x2 r;
    r.x = __uint_as_float(u << 16);
    r.y = __uint_as_float(u & 0xffff0000u);
    return r;
}
// tanh-form GELU via sigmoid: x * sigmoid(1.595769x + 0.0713548x^3); |err vs exact| <= ~3e-4
__device__ __forceinline__ float gelu_t(float x) {
    float x2 = x * x;
    float y = x * fmaf(0.0713548162726f, x2, 1.59576912161f);
    return x / (1.f + __expf(-y));
}

// f32 vector pack offsets (floats)
#define Vbp   0
#define Vatt1 128
#define Vb1   256
#define Vg1   384
#define Vbe1  512
#define Vatt2 640
#define Vb2   768
#define Vg2   896
#define Vbe2  1024
#define Vbo   1152
#define VTOT  1216

// bf16 transposed weight pack offsets (u16 elements)
#define BWp   0        // [128][64]  (K=40 zero-padded to 64)
#define BW1l  8192     // [128][128]
#define BW1r  24576    // adjacent to BW1l (gridDim.y=2 panel trick)
#define BW2l  40960
#define BW2r  57344
#define BWo   73728    // [64][128], padded to 128 rows (zeros)
#define BTOT  90112

// ---------------- dtype sniff ----------------
__global__ void sniff_kernel(const u32* __restrict__ ei_raw, const u32* __restrict__ x_raw,
                             int* __restrict__ flags) {
    if (threadIdx.x != 0 || blockIdx.x != 0) return;
    int allz = 1;
    for (int i = 1; i < 256; i += 2) allz &= (ei_raw[i] == 0u);
    flags[0] = allz;
    int bf_like = 0;
    for (int i = 0; i < 64; i++) {
        u16 lo = (u16)(x_raw[i] & 0xffffu);
        int e = (lo >> 7) & 0xFF;
        if (e >= 118 && e <= 133) bf_like++;
    }
    flags[1] = (bf_like >= 48) ? 1 : 0;
}

__device__ __forceinline__ void edge_decode(const int* __restrict__ ei, int is64, int e,
                                            int& src, int& dst) {
    if (e < EE) {
        src = is64 ? ei[2 * e] : ei[e];
        int idx = EE + e;
        dst = is64 ? ei[2 * idx] : ei[idx];
    } else {
        src = e - EE; dst = src;
    }
}

// ---------------- normalize x -> bf16 ----------------
__global__ void normx_kernel(const void* __restrict__ in, u16* __restrict__ out, int n,
                             const int* __restrict__ flags) {
    int i = blockIdx.x * 256 + threadIdx.x;
    if (i >= n) return;
    out[i] = flags[1] ? ((const u16*)in)[i] : f2bf(((const float*)in)[i]);
}

// ---------------- pack small vectors to f32 ----------------
__global__ void norm_vec_kernel(
    const void* p0, const void* p1, const void* p2, const void* p3, const void* p4,
    const void* p5, const void* p6, const void* p7, const void* p8, const void* p9,
    float* __restrict__ out, const int* __restrict__ flags)
{
    int i = blockIdx.x * 256 + threadIdx.x;
    if (i >= VTOT) return;
    const int offs[11] = {Vbp, Vatt1, Vb1, Vg1, Vbe1, Vatt2, Vb2, Vg2, Vbe2, Vbo, VTOT};
    const void* ps[10] = {p0,p1,p2,p3,p4,p5,p6,p7,p8,p9};
    int s = 0;
#pragma unroll
    for (int k = 1; k < 10; k++) s += (i >= offs[k]) ? 1 : 0;
    int j = i - offs[s];
    const void* p = ps[s];
    out[i] = flags[1] ? bf2f(((const u16*)p)[j]) : ((const float*)p)[j];
}

// ---------------- transpose weights to bf16 Wt[n][k] ----------------
__global__ void norm_wt_kernel(
    const void* w0, const void* w1, const void* w2, const void* w3, const void* w4,
    const void* w5, u16* __restrict__ out, const int* __restrict__ flags)
{
    int i = blockIdx.x * 256 + threadIdx.x;
    if (i >= BTOT) return;
    const int offs[7] = {BWp, BW1l, BW1r, BW2l, BW2r, BWo, BTOT};
    const int Ks[6]   = {40, 128, 128, 128, 128, 128};
    const int Ncs[6]  = {128, 128, 128, 128, 128, 64};
    const int Kps[6]  = {64, 128, 128, 128, 128, 128};
    const void* ps[6] = {w0,w1,w2,w3,w4,w5};
    int s = 0;
#pragma unroll
    for (int k = 1; k < 6; k++) s += (i >= offs[k]) ? 1 : 0;
    int j = i - offs[s];
    int Kp = Kps[s];
    int n = j / Kp, k = j % Kp;
    u16 v = 0;
    if (k < Ks[s] && n < Ncs[s]) {
        const void* p = ps[s];
        int src = k * Ncs[s] + n;
        v = flags[1] ? ((const u16*)p)[src] : f2bf(((const float*)p)[src]);
    }
    out[i] = v;
}

// ---------------- CSR build: 2-pass LDS-binned counting sort ----------------
__global__ __launch_bounds__(256) void bucket_hist_kernel(
    const int* __restrict__ ei, const int* __restrict__ flags, u32* __restrict__ gbucket)
{
    __shared__ u32 h[512];
    int t = threadIdx.x;
    h[t] = 0; h[t + 256] = 0;
    __syncthreads();
    int is64 = flags[0];
    int base = blockIdx.x * CHUNK;
#pragma unroll
    for (int j = 0; j < CHUNK / 256; j++) {
        int e = base + j * 256 + t;
        if (e < ETOT) {
            int src, dst;
            edge_decode(ei, is64, e, src, dst);
            atomicAdd(&h[dst >> 8], 1u);
        }
    }
    __syncthreads();
    if (h[t])       atomicAdd(&gbucket[t], h[t]);
    if (h[t + 256]) atomicAdd(&gbucket[t + 256], h[t + 256]);
}

__global__ __launch_bounds__(256) void bucket_scan_kernel(
    const u32* __restrict__ gbucket, u32* __restrict__ bbase, u32* __restrict__ bcursor)
{
    __shared__ u32 ts[256];
    int t = threadIdx.x;
    u32 s0 = (2 * t     < NB) ? gbucket[2 * t]     : 0;
    u32 s1 = (2 * t + 1 < NB) ? gbucket[2 * t + 1] : 0;
    u32 tsum = s0 + s1;
    ts[t] = tsum; __syncthreads();
    for (int d = 1; d < 256; d <<= 1) {
        u32 v = (t >= d) ? ts[t - d] : 0;
        __syncthreads();
        ts[t] += v;
        __syncthreads();
    }
    u32 excl = ts[t] - tsum;
    bbase[2 * t] = excl;          bcursor[2 * t] = excl;
    bbase[2 * t + 1] = excl + s0; bcursor[2 * t + 1] = excl + s0;
    if (2 * t == NB - 1 || 2 * t + 1 == NB - 1) bbase[NB] = ETOT;
}

__global__ __launch_bounds__(256) void bin_pass_kernel(
    const int* __restrict__ ei, const int* __restrict__ flags,
    u32* __restrict__ bcursor, u64* __restrict__ pairs)
{
    __shared__ u32 bh[512];
    __shared__ u32 boff[512];
    __shared__ u32 bbs[512];
    __shared__ u32 bcur[512];
    __shared__ u64 stage[CHUNK];
    __shared__ u32 ts[256];

    int t = threadIdx.x;
    bh[t] = 0; bh[t + 256] = 0;
    __syncthreads();
    int is64 = flags[0];
    int base = blockIdx.x * CHUNK;
    int chunk_n = ETOT - base; if (chunk_n > CHUNK) chunk_n = CHUNK;

#pragma unroll
    for (int j = 0; j < CHUNK / 256; j++) {
        int e = base + j * 256 + t;
        if (e < ETOT) {
            int src, dst;
            edge_decode(ei, is64, e, src, dst);
            atomicAdd(&bh[dst >> 8], 1u);
        }
    }
    __syncthreads();
    u32 s0 = bh[2 * t], s1 = bh[2 * t + 1];
    u32 tsum = s0 + s1;
    ts[t] = tsum; __syncthreads();
    for (int d = 1; d < 256; d <<= 1) {
        u32 v = (t >= d) ? ts[t - d] : 0;
        __syncthreads();
        ts[t] += v;
        __syncthreads();
    }
    u32 excl = ts[t] - tsum;
    boff[2 * t] = excl; boff[2 * t + 1] = excl + s0;
    bcur[2 * t] = excl; bcur[2 * t + 1] = excl + s0;
    __syncthreads();
    if (t < NB && bh[t]) bbs[t] = atomicAdd(&bcursor[t], bh[t]);
    if (t + 256 < NB && bh[t + 256]) bbs[t + 256] = atomicAdd(&bcursor[t + 256], bh[t + 256]);
    __syncthreads();
#pragma unroll
    for (int j = 0; j < CHUNK / 256; j++) {
        int e = base + j * 256 + t;
        if (e < ETOT) {
            int src, dst;
            edge_decode(ei, is64, e, src, dst);
            u32 pos = atomicAdd(&bcur[dst >> 8], 1u);
            stage[pos] = (u64)src | ((u64)dst << 32);
        }
    }
    __syncthreads();
    for (int i = t; i < chunk_n; i += 256) {
        u64 pr = stage[i];
        u32 b = (u32)(pr >> 32) >> 8;
        pairs[(size_t)bbs[b] + (i - boff[b])] = pr;
    }
}

__global__ __launch_bounds__(256) void sort_pass_kernel(
    const u64* __restrict__ pairs, const u32* __restrict__ bbase,
    int* __restrict__ srcs, int* __restrict__ offs)
{
    __shared__ u32 nh[256];
    __shared__ u32 ns[256];
    __shared__ u32 ncur[256];
    int t = threadIdx.x;
    int b = blockIdx.x;
    u32 beg = bbase[b], endp = bbase[b + 1];
    nh[t] = 0;
    __syncthreads();
    for (u32 i = beg + t; i < endp; i += 256) {
        u32 dst = (u32)(pairs[i] >> 32);
        atomicAdd(&nh[dst & 255], 1u);
    }
    __syncthreads();
    u32 cnt = nh[t];
    ns[t] = cnt; __syncthreads();
    for (int d = 1; d < 256; d <<= 1) {
        u32 v = (t >= d) ? ns[t - d] : 0;
        __syncthreads();
        ns[t] += v;
        __syncthreads();
    }
    u32 excl = ns[t] - cnt;
    int id = b * 256 + t;
    if (id <= NN) offs[id] = (int)(beg + excl);
    ncur[t] = excl;
    __syncthreads();
    for (u32 i = beg + t; i < endp; i += 256) {
        u64 pr = pairs[i];
        u32 loc = ((u32)(pr >> 32)) & 255;
        u32 p = atomicAdd(&ncur[loc], 1u);
        srcs[beg + p] = (int)(u32)pr;
    }
}

// ---------------- MFMA GEMM ----------------
__global__ __launch_bounds__(256) void mfma_gemm(
    const u16* __restrict__ A, int lda,
    const u16* __restrict__ Bt, int ldb,
    const float* __restrict__ bias,
    int nrows, int ksteps, int ncols,
    float* __restrict__ outF, u16* __restrict__ outB, u16* __restrict__ outB2, int ldo,
    int mode, const int* __restrict__ flags)
{
    int lane = threadIdx.x & 63;
    int wv = threadIdx.x >> 6;
    int wx = wv & 1, wy = wv >> 1;
    int l16 = lane & 15, quad = lane >> 4;
    int r0 = blockIdx.x * 128 + wx * 64;
    int n0 = wy * 64;

    Bt += (size_t)blockIdx.y * 128 * ldb;
    if (blockIdx.y) outB = outB2;

    f32x4 acc[4][4];
#pragma unroll
    for (int m = 0; m < 4; m++)
#pragma unroll
        for (int n = 0; n < 4; n++) acc[m][n] = (f32x4){0.f, 0.f, 0.f, 0.f};

    const u16* Ap = A + (size_t)(r0 + l16) * lda + quad * 8;
    const u16* Bp = Bt + (size_t)(n0 + l16) * ldb + quad * 8;

    for (int k = 0; k < ksteps; ++k) {
        bf16x8 af[4], bfr[4];
#pragma unroll
        for (int m = 0; m < 4; m++)
            af[m] = *(const bf16x8*)(Ap + (size_t)m * 16 * lda + k * 32);
#pragma unroll
        for (int n = 0; n < 4; n++)
            bfr[n] = *(const bf16x8*)(Bp + (size_t)n * 16 * ldb + k * 32);
#pragma unroll
        for (int m = 0; m < 4; m++)
#pragma unroll
            for (int n = 0; n < 4; n++)
                acc[m][n] = __builtin_amdgcn_mfma_f32_16x16x32_bf16(af[m], bfr[n], acc[m][n], 0, 0, 0);
    }

    int mk = mode;
    if (mk < 0) mk = flags[1] ? 2 : 1;

#pragma unroll
    for (int m = 0; m < 4; m++) {
#pragma unroll
        for (int n = 0; n < 4; n++) {
            int col = n0 + n * 16 + l16;
            float bb = (bias != nullptr && col < ncols) ? bias[col] : 0.f;
#pragma unroll
            for (int reg = 0; reg < 4; reg++) {
                int row = r0 + m * 16 + quad * 4 + reg;
                if (row < nrows && col < ncols) {
                    float v = acc[m][n][reg] + bb;
                    if (mk & 1) outF[(size_t)row * ldo + col] = v;
                    if (mk & 2) outB[(size_t)row * ldo + col] = f2bf(v);
                }
            }
        }
    }
}

// ---------------- fused GATv2 agg + bias + GELU + residual + LayerNorm ----------------
// one wave per dst; 4 edges in flight (g=lane>>4), lane r=lane&15 owns ch r*8..r*8+7
// packed-fp32 (v_pk_*) math on f32x2 lanes; bf16 residual in, bf16 out only
__global__ __launch_bounds__(256) void gat_agg_kernel(
    const u16* __restrict__ hl, const u16* __restrict__ hr, const u16* __restrict__ hresb,
    const float* __restrict__ att, const float* __restrict__ bias,
    const float* __restrict__ gamma, const float* __restrict__ beta,
    const int* __restrict__ offs, const int* __restrict__ srcs,
    u16* __restrict__ outb)
{
    int dst  = (blockIdx.x * 256 + threadIdx.x) >> 6;
    int lane = threadIdx.x & 63;
    int g = lane >> 4;
    int r = lane & 15;
    int c0 = r * 8;

    int start = offs[dst], end = offs[dst + 1];

    f32x2 hr2[4], av2[4];
    {
        uint4 q = *(const uint4*)(hr + ((size_t)dst << 7) + c0);
        hr2[0] = unpk(q.x); hr2[1] = unpk(q.y); hr2[2] = unpk(q.z); hr2[3] = unpk(q.w);
        float4 a0 = *(const float4*)&att[c0];
        float4 a1 = *(const float4*)&att[c0 + 4];
        av2[0] = (f32x2){a0.x, a0.y}; av2[1] = (f32x2){a0.z, a0.w};
        av2[2] = (f32x2){a1.x, a1.y}; av2[3] = (f32x2){a1.z, a1.w};
    }

    f32x2 acc2[4];
#pragma unroll
    for (int i = 0; i < 4; i++) acc2[i] = (f32x2){0.f, 0.f};
    float s = 0.f;

    int iters = (end - start + 3) >> 2;
    for (int j = 0; j < iters; ++j) {
        int e = start + j * 4 + g;
        bool valid = e < end;
        int src = srcs[valid ? e : (end - 1)];
        uint4 q = *(const uint4*)(hl + ((size_t)src << 7) + c0);
        f32x2 h2[4];
        h2[0] = unpk(q.x); h2[1] = unpk(q.y); h2[2] = unpk(q.z); h2[3] = unpk(q.w);
        f32x2 p2 = (f32x2){0.f, 0.f};
#pragma unroll
        for (int i = 0; i < 4; i++) {
            f32x2 z = h2[i] + hr2[i];
            f32x2 lz = __builtin_elementwise_max(z, z * 0.2f);
            p2 = __builtin_elementwise_fma(av2[i], lz, p2);
        }
        float p = p2.x + p2.y;
        p += __shfl_xor(p, 1);
        p += __shfl_xor(p, 2);
        float w = valid ? __expf(p) : 0.f;
        s += w;
        f32x2 w2 = (f32x2){w, w};
#pragma unroll
        for (int i = 0; i < 4; i++) acc2[i] = __builtin_elementwise_fma(w2, h2[i], acc2[i]);
    }

    // merge the 4 edge-groups (lanes differing in bits 4-5)
#pragma unroll
    for (int off = 16; off < 64; off <<= 1) {
        s += __shfl_xor(s, off);
#pragma unroll
        for (int i = 0; i < 4; i++) {
            float ax = acc2[i].x, ay = acc2[i].y;
            ax += __shfl_xor(ax, off);
            ay += __shfl_xor(ay, off);
            acc2[i] = (f32x2){ax, ay};
        }
    }

    float inv = 1.f / s;
    float v[8];
    {
        float4 b0 = *(const float4*)&bias[c0];
        float4 b1 = *(const float4*)&bias[c0 + 4];
        float bb[8] = {b0.x,b0.y,b0.z,b0.w,b1.x,b1.y,b1.z,b1.w};
        uint4 qr = *(const uint4*)(hresb + ((size_t)dst << 7) + c0);
        f32x2 rr2[4] = {unpk(qr.x), unpk(qr.y), unpk(qr.z), unpk(qr.w)};
#pragma unroll
        for (int i = 0; i < 4; i++) {
            float t0 = fmaf(acc2[i].x, inv, bb[2*i]);
            float t1 = fmaf(acc2[i].y, inv, bb[2*i+1]);
            v[2*i]   = gelu_t(t0) + rr2[i].x;
            v[2*i+1] = gelu_t(t1) + rr2[i].y;
        }
    }

    // LayerNorm over 128 ch
    float s1 = 0.f, s2 = 0.f;
#pragma unroll
    for (int k = 0; k < 8; k++) { s1 += v[k]; s2 = fmaf(v[k], v[k], s2); }
#pragma unroll
    for (int off = 1; off < 16; off <<= 1) {
        s1 += __shfl_xor(s1, off);
        s2 += __shfl_xor(s2, off);
    }
    float mu  = s1 * (1.f / 128.f);
    float var = s2 * (1.f / 128.f) - mu * mu;
    float rstd = rsqrtf(var + 1e-5f);

    if (g == 0) {
        float4 g0 = *(const float4*)&gamma[c0];
        float4 g1 = *(const float4*)&gamma[c0 + 4];
        float4 be0 = *(const float4*)&beta[c0];
        float4 be1 = *(const float4*)&beta[c0 + 4];
        float gg[8] = {g0.x,g0.y,g0.z,g0.w,g1.x,g1.y,g1.z,g1.w};
        float eb[8] = {be0.x,be0.y,be0.z,be0.w,be1.x,be1.y,be1.z,be1.w};
        float o[8];
#pragma unroll
        for (int k = 0; k < 8; k++) o[k] = fmaf((v[k] - mu) * rstd, gg[k], eb[k]);
        uint4 pk;
        pk.x = (u32)f2bf(o[0]) | ((u32)f2bf(o[1]) << 16);
        pk.y = (u32)f2bf(o[2]) | ((u32)f2bf(o[3]) << 16);
        pk.z = (u32)f2bf(o[4]) | ((u32)f2bf(o[5]) << 16);
        pk.w = (u32)f2bf(o[6]) | ((u32)f2bf(o[7]) << 16);
        *(uint4*)(outb + ((size_t)dst << 7) + c0) = pk;
    }
}

// ---------------- launch ----------------
extern "C" void kernel_launch(void* const* d_in, const int* in_sizes, int n_in,
                              void* d_out, int out_size, void* d_ws, size_t ws_size,
                              hipStream_t stream) {
    const void* x  = d_in[0];
    const int*  ei = (const int*)d_in[1];

    char* ws = (char*)d_ws;
    size_t off = 0;
    auto alloc = [&](size_t bytes) -> void* {
        void* p = ws + off;
        off = (off + bytes + 511) & ~(size_t)511;
        return p;
    };
    u16*   xb      = (u16*)  alloc(((size_t)NN * MM + 8192) * 2);
    float* wv      = (float*)alloc((size_t)VTOT * 4);
    u16*   wbf     = (u16*)  alloc((size_t)BTOT * 2);
    u16*   h0b     = (u16*)  alloc((size_t)(NN + 64) * HID * 2);
    u16*   h1b     = (u16*)  alloc((size_t)(NN + 64) * HID * 2);
    u16*   hlb     = (u16*)  alloc((size_t)NN * HID * 2);
    u16*   hrb     = (u16*)  alloc((size_t)NN * HID * 2);
    int*   offs    = (int*)  alloc((size_t)(NN + 1) * 4);
    u32*   gbucket = (u32*)  alloc(512 * 4);
    u32*   bbase   = (u32*)  alloc(520 * 4);
    u32*   bcursor = (u32*)  alloc(520 * 4);
    int*   flags   = (int*)  alloc(512);
    int*   srcs    = (int*)  alloc((size_t)ETOT * 4);
    u64*   pairs   = (u64*)  alloc((size_t)ETOT * 8);

    hipMemsetAsync(gbucket, 0, 512 * 4, stream);

    sniff_kernel<<<1, 64, 0, stream>>>((const u32*)ei, (const u32*)x, flags);

    normx_kernel<<<(NN * MM + 255) / 256, 256, 0, stream>>>(x, xb, NN * MM, flags);
    norm_vec_kernel<<<(VTOT + 255) / 256, 256, 0, stream>>>(
        d_in[3], d_in[6], d_in[7], d_in[12], d_in[13], d_in[10], d_in[11], d_in[14], d_in[15], d_in[17],
        wv, flags);
    norm_wt_kernel<<<(BTOT + 255) / 256, 256, 0, stream>>>(
        d_in[2], d_in[4], d_in[5], d_in[8], d_in[9], d_in[16], wbf, flags);

    const int EB = (ETOT + CHUNK - 1) / CHUNK;  // 416
    bucket_hist_kernel<<<EB, 256, 0, stream>>>(ei, flags, gbucket);
    bucket_scan_kernel<<<1, 256, 0, stream>>>(gbucket, bbase, bcursor);
    bin_pass_kernel<<<EB, 256, 0, stream>>>(ei, flags, bcursor, pairs);
    sort_pass_kernel<<<NB, 256, 0, stream>>>(pairs, bbase, srcs, offs);

    const int GB = (NN + 127) / 128;  // 782

    // proj: h0b = bf16(x @ Wp + bp)   (K=40 padded to 64)
    mfma_gemm<<<dim3(GB, 1), 256, 0, stream>>>(xb, MM, wbf + BWp, 64, wv + Vbp,
                                               NN, 2, HID, nullptr, h0b, nullptr, HID, 2, flags);

    // layer 1: hl/hr in one dispatch
    mfma_gemm<<<dim3(GB, 2), 256, 0, stream>>>(h0b, HID, wbf + BW1l, HID, nullptr,
                                               NN, 4, HID, nullptr, hlb, hrb, HID, 2, flags);
    gat_agg_kernel<<<NN / 4, 256, 0, stream>>>(hlb, hrb, h0b, wv + Vatt1, wv + Vb1,
                                               wv + Vg1, wv + Vbe1, offs, srcs, h1b);

    // layer 2
    mfma_gemm<<<dim3(GB, 2), 256, 0, stream>>>(h1b, HID, wbf + BW2l, HID, nullptr,
                                               NN, 4, HID, nullptr, hlb, hrb, HID, 2, flags);
    gat_agg_kernel<<<NN / 4, 256, 0, stream>>>(hlb, hrb, h1b, wv + Vatt2, wv + Vb2,
                                               wv + Vg2, wv + Vbe2, offs, srcs, h0b);

    // final: out = h @ Wo + bo (dtype per flags)
    mfma_gemm<<<dim3(GB, 1), 256, 0, stream>>>(h0b, HID, wbf + BWo, HID, wv + Vbo,
                                               NN, 4, LAT, (float*)d_out, (u16*)d_out, nullptr, LAT, -1, flags);
}

// Round 6
// 536.576 us; speedup vs baseline: 1.9163x; 1.0341x over previous
//
#include <hip/hip_runtime.h>
#include <hip/hip_bf16.h>
#include <math.h>

#define NN   100000
#define EE   1600000
#define ETOT 1700000   // EE + NN self loops
#define MM   40
#define HID  128
#define LAT  64
#define NB   391       // ceil(NN/256) buckets of 256 nodes
#define CHUNK 4096     // edges per bin_pass block

typedef unsigned short u16;
typedef unsigned int   u32;
typedef unsigned long long u64;

typedef __attribute__((ext_vector_type(8))) short bf16x8;
typedef __attribute__((ext_vector_type(4))) float f32x4;
typedef __attribute__((ext_vector_type(2))) float f32x2;

__device__ __forceinline__ float bf2f(u16 a) {
    return __uint_as_float(((u32)a) << 16);
}
__device__ __forceinline__ u16 f2bf(float f) {
    u32 u = __float_as_uint(f);
    u32 r = (u + 0x7fffu + ((u >> 16) & 1u)) >> 16;
    return (u16)r;
}
__device__ __forceinline__ f32x2 unpk(u32 u) {
    f32x2 r;
    r.x = __uint_as_float(u << 16);
    r.y = __uint_as_float(u & 0xffff0000u);
    return r;
}
// tanh-form GELU via sigmoid: x * sigmoid(1.595769x + 0.0713548x^3); |err vs exact| <= ~3e-4
__device__ __forceinline__ float gelu_t(float x) {
    float x2 = x * x;
    float y = x * fmaf(0.0713548162726f, x2, 1.59576912161f);
    return x / (1.f + __expf(-y));
}

// f32 vector pack offsets (floats)
#define Vbp   0
#define Vatt1 128
#define Vb1   256
#define Vg1   384
#define Vbe1  512
#define Vatt2 640
#define Vb2   768
#define Vg2   896
#define Vbe2  1024
#define Vbo   1152
#define VTOT  1216

// bf16 transposed weight pack offsets (u16 elements)
#define BWp   0        // [128][64]  (K=40 zero-padded to 64)
#define BW1l  8192     // [128][128]
#define BW1r  24576    // adjacent to BW1l (gridDim.y=2 panel trick)
#define BW2l  40960
#define BW2r  57344
#define BWo   73728    // [64][128], padded to 128 rows (zeros)
#define BTOT  90112

// ---------------- dtype sniff ----------------
__global__ void sniff_kernel(const u32* __restrict__ ei_raw, const u32* __restrict__ x_raw,
                             int* __restrict__ flags) {
    if (threadIdx.x != 0 || blockIdx.x != 0) return;
    int allz = 1;
    for (int i = 1; i < 256; i += 2) allz &= (ei_raw[i] == 0u);
    flags[0] = allz;
    int bf_like = 0;
    for (int i = 0; i < 64; i++) {
        u16 lo = (u16)(x_raw[i] & 0xffffu);
        int e = (lo >> 7) & 0xFF;
        if (e >= 118 && e <= 133) bf_like++;
    }
    flags[1] = (bf_like >= 48) ? 1 : 0;
}

__device__ __forceinline__ void edge_decode(const int* __restrict__ ei, int is64, int e,
                                            int& src, int& dst) {
    if (e < EE) {
        src = is64 ? ei[2 * e] : ei[e];
        int idx = EE + e;
        dst = is64 ? ei[2 * idx] : ei[idx];
    } else {
        src = e - EE; dst = src;
    }
}

// ---------------- normalize x -> bf16 ----------------
__global__ void normx_kernel(const void* __restrict__ in, u16* __restrict__ out, int n,
                             const int* __restrict__ flags) {
    int i = blockIdx.x * 256 + threadIdx.x;
    if (i >= n) return;
    out[i] = flags[1] ? ((const u16*)in)[i] : f2bf(((const float*)in)[i]);
}

// ---------------- pack small vectors to f32 ----------------
__global__ void norm_vec_kernel(
    const void* p0, const void* p1, const void* p2, const void* p3, const void* p4,
    const void* p5, const void* p6, const void* p7, const void* p8, const void* p9,
    float* __restrict__ out, const int* __restrict__ flags)
{
    int i = blockIdx.x * 256 + threadIdx.x;
    if (i >= VTOT) return;
    const int offs[11] = {Vbp, Vatt1, Vb1, Vg1, Vbe1, Vatt2, Vb2, Vg2, Vbe2, Vbo, VTOT};
    const void* ps[10] = {p0,p1,p2,p3,p4,p5,p6,p7,p8,p9};
    int s = 0;
#pragma unroll
    for (int k = 1; k < 10; k++) s += (i >= offs[k]) ? 1 : 0;
    int j = i - offs[s];
    const void* p = ps[s];
    out[i] = flags[1] ? bf2f(((const u16*)p)[j]) : ((const float*)p)[j];
}

// ---------------- transpose weights to bf16 Wt[n][k] ----------------
__global__ void norm_wt_kernel(
    const void* w0, const void* w1, const void* w2, const void* w3, const void* w4,
    const void* w5, u16* __restrict__ out, const int* __restrict__ flags)
{
    int i = blockIdx.x * 256 + threadIdx.x;
    if (i >= BTOT) return;
    const int offs[7] = {BWp, BW1l, BW1r, BW2l, BW2r, BWo, BTOT};
    const int Ks[6]   = {40, 128, 128, 128, 128, 128};
    const int Ncs[6]  = {128, 128, 128, 128, 128, 64};
    const int Kps[6]  = {64, 128, 128, 128, 128, 128};
    const void* ps[6] = {w0,w1,w2,w3,w4,w5};
    int s = 0;
#pragma unroll
    for (int k = 1; k < 6; k++) s += (i >= offs[k]) ? 1 : 0;
    int j = i - offs[s];
    int Kp = Kps[s];
    int n = j / Kp, k = j % Kp;
    u16 v = 0;
    if (k < Ks[s] && n < Ncs[s]) {
        const void* p = ps[s];
        int src = k * Ncs[s] + n;
        v = flags[1] ? ((const u16*)p)[src] : f2bf(((const float*)p)[src]);
    }
    out[i] = v;
}

// ---------------- CSR build: 2-pass LDS-binned counting sort ----------------
__global__ __launch_bounds__(256) void bucket_hist_kernel(
    const int* __restrict__ ei, const int* __restrict__ flags, u32* __restrict__ gbucket)
{
    __shared__ u32 h[512];
    int t = threadIdx.x;
    h[t] = 0; h[t + 256] = 0;
    __syncthreads();
    int is64 = flags[0];
    int base = blockIdx.x * CHUNK;
#pragma unroll
    for (int j = 0; j < CHUNK / 256; j++) {
        int e = base + j * 256 + t;
        if (e < ETOT) {
            int src, dst;
            edge_decode(ei, is64, e, src, dst);
            atomicAdd(&h[dst >> 8], 1u);
        }
    }
    __syncthreads();
    if (h[t])       atomicAdd(&gbucket[t], h[t]);
    if (h[t + 256]) atomicAdd(&gbucket[t + 256], h[t + 256]);
}

__global__ __launch_bounds__(256) void bucket_scan_kernel(
    const u32* __restrict__ gbucket, u32* __restrict__ bbase, u32* __restrict__ bcursor)
{
    __shared__ u32 ts[256];
    int t = threadIdx.x;
    u32 s0 = (2 * t     < NB) ? gbucket[2 * t]     : 0;
    u32 s1 = (2 * t + 1 < NB) ? gbucket[2 * t + 1] : 0;
    u32 tsum = s0 + s1;
    ts[t] = tsum; __syncthreads();
    for (int d = 1; d < 256; d <<= 1) {
        u32 v = (t >= d) ? ts[t - d] : 0;
        __syncthreads();
        ts[t] += v;
        __syncthreads();
    }
    u32 excl = ts[t] - tsum;
    bbase[2 * t] = excl;          bcursor[2 * t] = excl;
    bbase[2 * t + 1] = excl + s0; bcursor[2 * t + 1] = excl + s0;
    if (2 * t == NB - 1 || 2 * t + 1 == NB - 1) bbase[NB] = ETOT;
}

__global__ __launch_bounds__(256) void bin_pass_kernel(
    const int* __restrict__ ei, const int* __restrict__ flags,
    u32* __restrict__ bcursor, u64* __restrict__ pairs)
{
    __shared__ u32 bh[512];
    __shared__ u32 boff[512];
    __shared__ u32 bbs[512];
    __shared__ u32 bcur[512];
    __shared__ u64 stage[CHUNK];
    __shared__ u32 ts[256];

    int t = threadIdx.x;
    bh[t] = 0; bh[t + 256] = 0;
    __syncthreads();
    int is64 = flags[0];
    int base = blockIdx.x * CHUNK;
    int chunk_n = ETOT - base; if (chunk_n > CHUNK) chunk_n = CHUNK;

#pragma unroll
    for (int j = 0; j < CHUNK / 256; j++) {
        int e = base + j * 256 + t;
        if (e < ETOT) {
            int src, dst;
            edge_decode(ei, is64, e, src, dst);
            atomicAdd(&bh[dst >> 8], 1u);
        }
    }
    __syncthreads();
    u32 s0 = bh[2 * t], s1 = bh[2 * t + 1];
    u32 tsum = s0 + s1;
    ts[t] = tsum; __syncthreads();
    for (int d = 1; d < 256; d <<= 1) {
        u32 v = (t >= d) ? ts[t - d] : 0;
        __syncthreads();
        ts[t] += v;
        __syncthreads();
    }
    u32 excl = ts[t] - tsum;
    boff[2 * t] = excl; boff[2 * t + 1] = excl + s0;
    bcur[2 * t] = excl; bcur[2 * t + 1] = excl + s0;
    __syncthreads();
    if (t < NB && bh[t]) bbs[t] = atomicAdd(&bcursor[t], bh[t]);
    if (t + 256 < NB && bh[t + 256]) bbs[t + 256] = atomicAdd(&bcursor[t + 256], bh[t + 256]);
    __syncthreads();
#pragma unroll
    for (int j = 0; j < CHUNK / 256; j++) {
        int e = base + j * 256 + t;
        if (e < ETOT) {
            int src, dst;
            edge_decode(ei, is64, e, src, dst);
            u32 pos = atomicAdd(&bcur[dst >> 8], 1u);
            stage[pos] = (u64)src | ((u64)dst << 32);
        }
    }
    __syncthreads();
    for (int i = t; i < chunk_n; i += 256) {
        u64 pr = stage[i];
        u32 b = (u32)(pr >> 32) >> 8;
        pairs[(size_t)bbs[b] + (i - boff[b])] = pr;
    }
}

__global__ __launch_bounds__(256) void sort_pass_kernel(
    const u64* __restrict__ pairs, const u32* __restrict__ bbase,
    int* __restrict__ srcs, int* __restrict__ offs)
{
    __shared__ u32 nh[256];
    __shared__ u32 ns[256];
    __shared__ u32 ncur[256];
    int t = threadIdx.x;
    int b = blockIdx.x;
    u32 beg = bbase[b], endp = bbase[b + 1];
    nh[t] = 0;
    __syncthreads();
    for (u32 i = beg + t; i < endp; i += 256) {
        u32 dst = (u32)(pairs[i] >> 32);
        atomicAdd(&nh[dst & 255], 1u);
    }
    __syncthreads();
    u32 cnt = nh[t];
    ns[t] = cnt; __syncthreads();
    for (int d = 1; d < 256; d <<= 1) {
        u32 v = (t >= d) ? ns[t - d] : 0;
        __syncthreads();
        ns[t] += v;
        __syncthreads();
    }
    u32 excl = ns[t] - cnt;
    int id = b * 256 + t;
    if (id <= NN) offs[id] = (int)(beg + excl);
    ncur[t] = excl;
    __syncthreads();
    for (u32 i = beg + t; i < endp; i += 256) {
        u64 pr = pairs[i];
        u32 loc = ((u32)(pr >> 32)) & 255;
        u32 p = atomicAdd(&ncur[loc], 1u);
        srcs[beg + p] = (int)(u32)pr;
    }
}

// ---------------- MFMA GEMM ----------------
__global__ __launch_bounds__(256) void mfma_gemm(
    const u16* __restrict__ A, int lda,
    const u16* __restrict__ Bt, int ldb,
    const float* __restrict__ bias,
    int nrows, int ksteps, int ncols,
    float* __restrict__ outF, u16* __restrict__ outB, u16* __restrict__ outB2, int ldo,
    int mode, const int* __restrict__ flags)
{
    int lane = threadIdx.x & 63;
    int wv = threadIdx.x >> 6;
    int wx = wv & 1, wy = wv >> 1;
    int l16 = lane & 15, quad = lane >> 4;
    int r0 = blockIdx.x * 128 + wx * 64;
    int n0 = wy * 64;

    Bt += (size_t)blockIdx.y * 128 * ldb;
    if (blockIdx.y) outB = outB2;

    f32x4 acc[4][4];
#pragma unroll
    for (int m = 0; m < 4; m++)
#pragma unroll
        for (int n = 0; n < 4; n++) acc[m][n] = (f32x4){0.f, 0.f, 0.f, 0.f};

    const u16* Ap = A + (size_t)(r0 + l16) * lda + quad * 8;
    const u16* Bp = Bt + (size_t)(n0 + l16) * ldb + quad * 8;

    for (int k = 0; k < ksteps; ++k) {
        bf16x8 af[4], bfr[4];
#pragma unroll
        for (int m = 0; m < 4; m++)
            af[m] = *(const bf16x8*)(Ap + (size_t)m * 16 * lda + k * 32);
#pragma unroll
        for (int n = 0; n < 4; n++)
            bfr[n] = *(const bf16x8*)(Bp + (size_t)n * 16 * ldb + k * 32);
#pragma unroll
        for (int m = 0; m < 4; m++)
#pragma unroll
            for (int n = 0; n < 4; n++)
                acc[m][n] = __builtin_amdgcn_mfma_f32_16x16x32_bf16(af[m], bfr[n], acc[m][n], 0, 0, 0);
    }

    int mk = mode;
    if (mk < 0) mk = flags[1] ? 2 : 1;

#pragma unroll
    for (int m = 0; m < 4; m++) {
#pragma unroll
        for (int n = 0; n < 4; n++) {
            int col = n0 + n * 16 + l16;
            float bb = (bias != nullptr && col < ncols) ? bias[col] : 0.f;
#pragma unroll
            for (int reg = 0; reg < 4; reg++) {
                int row = r0 + m * 16 + quad * 4 + reg;
                if (row < nrows && col < ncols) {
                    float v = acc[m][n][reg] + bb;
                    if (mk & 1) outF[(size_t)row * ldo + col] = v;
                    if (mk & 2) outB[(size_t)row * ldo + col] = f2bf(v);
                }
            }
        }
    }
}

// ---------------- fused GATv2 agg + bias + GELU + residual + LayerNorm ----------------
// one wave per dst; 4 edges in flight (g=lane>>4), lane r=lane&15 owns ch r*8..r*8+7.
// srcs preloaded into a lane register (deg<=64) + depth-1 software-pipelined gather.
__global__ __launch_bounds__(256) void gat_agg_kernel(
    const u16* __restrict__ hl, const u16* __restrict__ hr, const u16* __restrict__ hresb,
    const float* __restrict__ att, const float* __restrict__ bias,
    const float* __restrict__ gamma, const float* __restrict__ beta,
    const int* __restrict__ offs, const int* __restrict__ srcs,
    u16* __restrict__ outb)
{
    int dst  = (blockIdx.x * 256 + threadIdx.x) >> 6;
    int lane = threadIdx.x & 63;
    int g = lane >> 4;
    int r = lane & 15;
    int c0 = r * 8;

    int start = offs[dst], end = offs[dst + 1];
    int deg = end - start;              // >= 1 (self loop)

    f32x2 hr2[4], av2[4];
    {
        uint4 q = *(const uint4*)(hr + ((size_t)dst << 7) + c0);
        hr2[0] = unpk(q.x); hr2[1] = unpk(q.y); hr2[2] = unpk(q.z); hr2[3] = unpk(q.w);
        float4 a0 = *(const float4*)&att[c0];
        float4 a1 = *(const float4*)&att[c0 + 4];
        av2[0] = (f32x2){a0.x, a0.y}; av2[1] = (f32x2){a0.z, a0.w};
        av2[2] = (f32x2){a1.x, a1.y}; av2[3] = (f32x2){a1.z, a1.w};
    }

    // preload srcs[start..start+63] into lane regs (one coalesced load)
    int ld = lane < deg ? lane : deg - 1;
    int my_src = srcs[start + ld];

    f32x2 acc2[4];
#pragma unroll
    for (int i = 0; i < 4; i++) acc2[i] = (f32x2){0.f, 0.f};
    float s = 0.f;

    int iters = (deg + 3) >> 2;
    int cap = iters < 16 ? iters : 16;   // register-resident phase: edges 0..63

    // prologue prefetch (j = 0)
    int e_cur = g;                       // may be >= deg for tiny nodes; clamp
    int idx0 = e_cur < deg ? e_cur : deg - 1;
    int src0 = __shfl(my_src, idx0);
    uint4 q_cur = *(const uint4*)(hl + ((size_t)src0 << 7) + c0);
    uint4 q_nxt;

    for (int j = 0; j < cap; ++j) {
        if (j + 1 < cap) {
            int en = (j + 1) * 4 + g;
            en = en < deg ? en : deg - 1;
            int sn = __shfl(my_src, en);
            q_nxt = *(const uint4*)(hl + ((size_t)sn << 7) + c0);
        }
        int e = j * 4 + g;
        bool valid = e < deg;
        f32x2 h2[4];
        h2[0] = unpk(q_cur.x); h2[1] = unpk(q_cur.y);
        h2[2] = unpk(q_cur.z); h2[3] = unpk(q_cur.w);
        f32x2 p2 = (f32x2){0.f, 0.f};
#pragma unroll
        for (int i = 0; i < 4; i++) {
            f32x2 z = h2[i] + hr2[i];
            f32x2 lz = __builtin_elementwise_max(z, z * 0.2f);
            p2 = __builtin_elementwise_fma(av2[i], lz, p2);
        }
        float p = p2.x + p2.y;
        p += __shfl_xor(p, 1);
        p += __shfl_xor(p, 2);
        float w = valid ? __expf(p) : 0.f;
        s += w;
        f32x2 w2 = (f32x2){w, w};
#pragma unroll
        for (int i = 0; i < 4; i++) acc2[i] = __builtin_elementwise_fma(w2, h2[i], acc2[i]);
        q_cur = q_nxt;
    }

    // tail for deg > 64 (vanishingly rare at Poisson(17); correctness fallback)
    for (int e4 = 64; e4 < deg; e4 += 4) {
        int e = e4 + g;
        bool valid = e < deg;
        int src = srcs[start + (valid ? e : deg - 1)];
        uint4 q = *(const uint4*)(hl + ((size_t)src << 7) + c0);
        f32x2 h2[4];
        h2[0] = unpk(q.x); h2[1] = unpk(q.y); h2[2] = unpk(q.z); h2[3] = unpk(q.w);
        f32x2 p2 = (f32x2){0.f, 0.f};
#pragma unroll
        for (int i = 0; i < 4; i++) {
            f32x2 z = h2[i] + hr2[i];
            f32x2 lz = __builtin_elementwise_max(z, z * 0.2f);
            p2 = __builtin_elementwise_fma(av2[i], lz, p2);
        }
        float p = p2.x + p2.y;
        p += __shfl_xor(p, 1);
        p += __shfl_xor(p, 2);
        float w = valid ? __expf(p) : 0.f;
        s += w;
        f32x2 w2 = (f32x2){w, w};
#pragma unroll
        for (int i = 0; i < 4; i++) acc2[i] = __builtin_elementwise_fma(w2, h2[i], acc2[i]);
    }

    // merge the 4 edge-groups (lanes differing in bits 4-5)
#pragma unroll
    for (int off = 16; off < 64; off <<= 1) {
        s += __shfl_xor(s, off);
#pragma unroll
        for (int i = 0; i < 4; i++) {
            float ax = acc2[i].x, ay = acc2[i].y;
            ax += __shfl_xor(ax, off);
            ay += __shfl_xor(ay, off);
            acc2[i] = (f32x2){ax, ay};
        }
    }

    float inv = 1.f / s;
    float v[8];
    {
        float4 b0 = *(const float4*)&bias[c0];
        float4 b1 = *(const float4*)&bias[c0 + 4];
        float bb[8] = {b0.x,b0.y,b0.z,b0.w,b1.x,b1.y,b1.z,b1.w};
        uint4 qr = *(const uint4*)(hresb + ((size_t)dst << 7) + c0);
        f32x2 rr2[4] = {unpk(qr.x), unpk(qr.y), unpk(qr.z), unpk(qr.w)};
#pragma unroll
        for (int i = 0; i < 4; i++) {
            float t0 = fmaf(acc2[i].x, inv, bb[2*i]);
            float t1 = fmaf(acc2[i].y, inv, bb[2*i+1]);
            v[2*i]   = gelu_t(t0) + rr2[i].x;
            v[2*i+1] = gelu_t(t1) + rr2[i].y;
        }
    }

    // LayerNorm over 128 ch
    float s1 = 0.f, s2 = 0.f;
#pragma unroll
    for (int k = 0; k < 8; k++) { s1 += v[k]; s2 = fmaf(v[k], v[k], s2); }
#pragma unroll
    for (int off = 1; off < 16; off <<= 1) {
        s1 += __shfl_xor(s1, off);
        s2 += __shfl_xor(s2, off);
    }
    float mu  = s1 * (1.f / 128.f);
    float var = s2 * (1.f / 128.f) - mu * mu;
    float rstd = rsqrtf(var + 1e-5f);

    if (g == 0) {
        float4 g0 = *(const float4*)&gamma[c0];
        float4 g1 = *(const float4*)&gamma[c0 + 4];
        float4 be0 = *(const float4*)&beta[c0];
        float4 be1 = *(const float4*)&beta[c0 + 4];
        float gg[8] = {g0.x,g0.y,g0.z,g0.w,g1.x,g1.y,g1.z,g1.w};
        float eb[8] = {be0.x,be0.y,be0.z,be0.w,be1.x,be1.y,be1.z,be1.w};
        float o[8];
#pragma unroll
        for (int k = 0; k < 8; k++) o[k] = fmaf((v[k] - mu) * rstd, gg[k], eb[k]);
        uint4 pk;
        pk.x = (u32)f2bf(o[0]) | ((u32)f2bf(o[1]) << 16);
        pk.y = (u32)f2bf(o[2]) | ((u32)f2bf(o[3]) << 16);
        pk.z = (u32)f2bf(o[4]) | ((u32)f2bf(o[5]) << 16);
        pk.w = (u32)f2bf(o[6]) | ((u32)f2bf(o[7]) << 16);
        *(uint4*)(outb + ((size_t)dst << 7) + c0) = pk;
    }
}

// ---------------- launch ----------------
extern "C" void kernel_launch(void* const* d_in, const int* in_sizes, int n_in,
                              void* d_out, int out_size, void* d_ws, size_t ws_size,
                              hipStream_t stream) {
    const void* x  = d_in[0];
    const int*  ei = (const int*)d_in[1];

    char* ws = (char*)d_ws;
    size_t off = 0;
    auto alloc = [&](size_t bytes) -> void* {
        void* p = ws + off;
        off = (off + bytes + 511) & ~(size_t)511;
        return p;
    };
    u16*   xb      = (u16*)  alloc(((size_t)NN * MM + 8192) * 2);
    float* wv      = (float*)alloc((size_t)VTOT * 4);
    u16*   wbf     = (u16*)  alloc((size_t)BTOT * 2);
    u16*   h0b     = (u16*)  alloc((size_t)(NN + 64) * HID * 2);
    u16*   h1b     = (u16*)  alloc((size_t)(NN + 64) * HID * 2);
    u16*   hlb     = (u16*)  alloc((size_t)NN * HID * 2);
    u16*   hrb     = (u16*)  alloc((size_t)NN * HID * 2);
    int*   offs    = (int*)  alloc((size_t)(NN + 1) * 4);
    u32*   gbucket = (u32*)  alloc(512 * 4);
    u32*   bbase   = (u32*)  alloc(520 * 4);
    u32*   bcursor = (u32*)  alloc(520 * 4);
    int*   flags   = (int*)  alloc(512);
    int*   srcs    = (int*)  alloc(((size_t)ETOT + 64) * 4);
    u64*   pairs   = (u64*)  alloc((size_t)ETOT * 8);

    hipMemsetAsync(gbucket, 0, 512 * 4, stream);

    sniff_kernel<<<1, 64, 0, stream>>>((const u32*)ei, (const u32*)x, flags);

    normx_kernel<<<(NN * MM + 255) / 256, 256, 0, stream>>>(x, xb, NN * MM, flags);
    norm_vec_kernel<<<(VTOT + 255) / 256, 256, 0, stream>>>(
        d_in[3], d_in[6], d_in[7], d_in[12], d_in[13], d_in[10], d_in[11], d_in[14], d_in[15], d_in[17],
        wv, flags);
    norm_wt_kernel<<<(BTOT + 255) / 256, 256, 0, stream>>>(
        d_in[2], d_in[4], d_in[5], d_in[8], d_in[9], d_in[16], wbf, flags);

    const int EB = (ETOT + CHUNK - 1) / CHUNK;  // 416
    bucket_hist_kernel<<<EB, 256, 0, stream>>>(ei, flags, gbucket);
    bucket_scan_kernel<<<1, 256, 0, stream>>>(gbucket, bbase, bcursor);
    bin_pass_kernel<<<EB, 256, 0, stream>>>(ei, flags, bcursor, pairs);
    sort_pass_kernel<<<NB, 256, 0, stream>>>(pairs, bbase, srcs, offs);

    const int GB = (NN + 127) / 128;  // 782

    // proj: h0b = bf16(x @ Wp + bp)   (K=40 padded to 64)
    mfma_gemm<<<dim3(GB, 1), 256, 0, stream>>>(xb, MM, wbf + BWp, 64, wv + Vbp,
                                               NN, 2, HID, nullptr, h0b, nullptr, HID, 2, flags);

    // layer 1: hl/hr in one dispatch
    mfma_gemm<<<dim3(GB, 2), 256, 0, stream>>>(h0b, HID, wbf + BW1l, HID, nullptr,
                                               NN, 4, HID, nullptr, hlb, hrb, HID, 2, flags);
    gat_agg_kernel<<<NN / 4, 256, 0, stream>>>(hlb, hrb, h0b, wv + Vatt1, wv + Vb1,
                                               wv + Vg1, wv + Vbe1, offs, srcs, h1b);

    // layer 2
    mfma_gemm<<<dim3(GB, 2), 256, 0, stream>>>(h1b, HID, wbf + BW2l, HID, nullptr,
                                               NN, 4, HID, nullptr, hlb, hrb, HID, 2, flags);
    gat_agg_kernel<<<NN / 4, 256, 0, stream>>>(hlb, hrb, h1b, wv + Vatt2, wv + Vb2,
                                               wv + Vg2, wv + Vbe2, offs, srcs, h0b);

    // final: out = h @ Wo + bo (dtype per flags)
    mfma_gemm<<<dim3(GB, 1), 256, 0, stream>>>(h0b, HID, wbf + BWo, HID, wv + Vbo,
                                               NN, 4, LAT, (float*)d_out, (u16*)d_out, nullptr, LAT, -1, flags);
}

// Round 7
// 510.531 us; speedup vs baseline: 2.0140x; 1.0510x over previous
//
#include <hip/hip_runtime.h>
#include <hip/hip_bf16.h>
#include <math.h>

#define NN   100000
#define EE   1600000
#define ETOT 1700000   // EE + NN self loops
#define MM   40
#define HID  128
#define LAT  64
#define NB   391       // ceil(NN/256) buckets of 256 nodes
#define CHUNK 4096     // edges per bin_pass block

typedef unsigned short u16;
typedef unsigned int   u32;
typedef unsigned long long u64;

typedef __attribute__((ext_vector_type(8))) short bf16x8;
typedef __attribute__((ext_vector_type(4))) float f32x4;
typedef __attribute__((ext_vector_type(2))) float f32x2;

__device__ __forceinline__ float bf2f(u16 a) {
    return __uint_as_float(((u32)a) << 16);
}
__device__ __forceinline__ u16 f2bf(float f) {
    u32 u = __float_as_uint(f);
    u32 r = (u + 0x7fffu + ((u >> 16) & 1u)) >> 16;
    return (u16)r;
}
__device__ __forceinline__ f32x2 unpk(u32 u) {
    f32x2 r;
    r.x = __uint_as_float(u << 16);
    r.y = __uint_as_float(u & 0xffff0000u);
    return r;
}
// tanh-form GELU via sigmoid: x * sigmoid(1.595769x + 0.0713548x^3); |err vs exact| <= ~3e-4
__device__ __forceinline__ float gelu_t(float x) {
    float x2 = x * x;
    float y = x * fmaf(0.0713548162726f, x2, 1.59576912161f);
    return x / (1.f + __expf(-y));
}

// f32 vector pack offsets (floats)
#define Vbp   0
#define Vatt1 128
#define Vb1   256
#define Vg1   384
#define Vbe1  512
#define Vatt2 640
#define Vb2   768
#define Vg2   896
#define Vbe2  1024
#define Vbo   1152
#define VTOT  1216

// bf16 transposed weight pack offsets (u16 elements)
#define BWp   0        // [128][64]  (K=40 zero-padded to 64)
#define BW1l  8192     // [128][128]
#define BW1r  24576    // adjacent to BW1l (gridDim.y=2 panel trick)
#define BW2l  40960
#define BW2r  57344
#define BWo   73728    // [64][128], padded to 128 rows (zeros)
#define BTOT  90112

// ---------------- dtype sniff ----------------
__global__ void sniff_kernel(const u32* __restrict__ ei_raw, const u32* __restrict__ x_raw,
                             int* __restrict__ flags) {
    if (threadIdx.x != 0 || blockIdx.x != 0) return;
    int allz = 1;
    for (int i = 1; i < 256; i += 2) allz &= (ei_raw[i] == 0u);
    flags[0] = allz;
    int bf_like = 0;
    for (int i = 0; i < 64; i++) {
        u16 lo = (u16)(x_raw[i] & 0xffffu);
        int e = (lo >> 7) & 0xFF;
        if (e >= 118 && e <= 133) bf_like++;
    }
    flags[1] = (bf_like >= 48) ? 1 : 0;
}

__device__ __forceinline__ void edge_decode(const int* __restrict__ ei, int is64, int e,
                                            int& src, int& dst) {
    if (e < EE) {
        src = is64 ? ei[2 * e] : ei[e];
        int idx = EE + e;
        dst = is64 ? ei[2 * idx] : ei[idx];
    } else {
        src = e - EE; dst = src;
    }
}

// ---------------- normalize x -> bf16 ----------------
__global__ void normx_kernel(const void* __restrict__ in, u16* __restrict__ out, int n,
                             const int* __restrict__ flags) {
    int i = blockIdx.x * 256 + threadIdx.x;
    if (i >= n) return;
    out[i] = flags[1] ? ((const u16*)in)[i] : f2bf(((const float*)in)[i]);
}

// ---------------- pack small vectors to f32 ----------------
__global__ void norm_vec_kernel(
    const void* p0, const void* p1, const void* p2, const void* p3, const void* p4,
    const void* p5, const void* p6, const void* p7, const void* p8, const void* p9,
    float* __restrict__ out, const int* __restrict__ flags)
{
    int i = blockIdx.x * 256 + threadIdx.x;
    if (i >= VTOT) return;
    const int offs[11] = {Vbp, Vatt1, Vb1, Vg1, Vbe1, Vatt2, Vb2, Vg2, Vbe2, Vbo, VTOT};
    const void* ps[10] = {p0,p1,p2,p3,p4,p5,p6,p7,p8,p9};
    int s = 0;
#pragma unroll
    for (int k = 1; k < 10; k++) s += (i >= offs[k]) ? 1 : 0;
    int j = i - offs[s];
    const void* p = ps[s];
    out[i] = flags[1] ? bf2f(((const u16*)p)[j]) : ((const float*)p)[j];
}

// ---------------- transpose weights to bf16 Wt[n][k] ----------------
__global__ void norm_wt_kernel(
    const void* w0, const void* w1, const void* w2, const void* w3, const void* w4,
    const void* w5, u16* __restrict__ out, const int* __restrict__ flags)
{
    int i = blockIdx.x * 256 + threadIdx.x;
    if (i >= BTOT) return;
    const int offs[7] = {BWp, BW1l, BW1r, BW2l, BW2r, BWo, BTOT};
    const int Ks[6]   = {40, 128, 128, 128, 128, 128};
    const int Ncs[6]  = {128, 128, 128, 128, 128, 64};
    const int Kps[6]  = {64, 128, 128, 128, 128, 128};
    const void* ps[6] = {w0,w1,w2,w3,w4,w5};
    int s = 0;
#pragma unroll
    for (int k = 1; k < 6; k++) s += (i >= offs[k]) ? 1 : 0;
    int j = i - offs[s];
    int Kp = Kps[s];
    int n = j / Kp, k = j % Kp;
    u16 v = 0;
    if (k < Ks[s] && n < Ncs[s]) {
        const void* p = ps[s];
        int src = k * Ncs[s] + n;
        v = flags[1] ? ((const u16*)p)[src] : f2bf(((const float*)p)[src]);
    }
    out[i] = v;
}

// ---------------- CSR build: 2-pass LDS-binned counting sort ----------------
__global__ __launch_bounds__(256) void bucket_hist_kernel(
    const int* __restrict__ ei, const int* __restrict__ flags, u32* __restrict__ gbucket)
{
    __shared__ u32 h[512];
    int t = threadIdx.x;
    h[t] = 0; h[t + 256] = 0;
    __syncthreads();
    int is64 = flags[0];
    int base = blockIdx.x * CHUNK;
#pragma unroll
    for (int j = 0; j < CHUNK / 256; j++) {
        int e = base + j * 256 + t;
        if (e < ETOT) {
            int src, dst;
            edge_decode(ei, is64, e, src, dst);
            atomicAdd(&h[dst >> 8], 1u);
        }
    }
    __syncthreads();
    if (h[t])       atomicAdd(&gbucket[t], h[t]);
    if (h[t + 256]) atomicAdd(&gbucket[t + 256], h[t + 256]);
}

__global__ __launch_bounds__(256) void bucket_scan_kernel(
    const u32* __restrict__ gbucket, u32* __restrict__ bbase, u32* __restrict__ bcursor)
{
    __shared__ u32 ts[256];
    int t = threadIdx.x;
    u32 s0 = (2 * t     < NB) ? gbucket[2 * t]     : 0;
    u32 s1 = (2 * t + 1 < NB) ? gbucket[2 * t + 1] : 0;
    u32 tsum = s0 + s1;
    ts[t] = tsum; __syncthreads();
    for (int d = 1; d < 256; d <<= 1) {
        u32 v = (t >= d) ? ts[t - d] : 0;
        __syncthreads();
        ts[t] += v;
        __syncthreads();
    }
    u32 excl = ts[t] - tsum;
    bbase[2 * t] = excl;          bcursor[2 * t] = excl;
    bbase[2 * t + 1] = excl + s0; bcursor[2 * t + 1] = excl + s0;
    if (2 * t == NB - 1 || 2 * t + 1 == NB - 1) bbase[NB] = ETOT;
}

__global__ __launch_bounds__(256) void bin_pass_kernel(
    const int* __restrict__ ei, const int* __restrict__ flags,
    u32* __restrict__ bcursor, u64* __restrict__ pairs)
{
    __shared__ u32 bh[512];
    __shared__ u32 boff[512];
    __shared__ u32 bbs[512];
    __shared__ u32 bcur[512];
    __shared__ u64 stage[CHUNK];
    __shared__ u32 ts[256];

    int t = threadIdx.x;
    bh[t] = 0; bh[t + 256] = 0;
    __syncthreads();
    int is64 = flags[0];
    int base = blockIdx.x * CHUNK;
    int chunk_n = ETOT - base; if (chunk_n > CHUNK) chunk_n = CHUNK;

#pragma unroll
    for (int j = 0; j < CHUNK / 256; j++) {
        int e = base + j * 256 + t;
        if (e < ETOT) {
            int src, dst;
            edge_decode(ei, is64, e, src, dst);
            atomicAdd(&bh[dst >> 8], 1u);
        }
    }
    __syncthreads();
    u32 s0 = bh[2 * t], s1 = bh[2 * t + 1];
    u32 tsum = s0 + s1;
    ts[t] = tsum; __syncthreads();
    for (int d = 1; d < 256; d <<= 1) {
        u32 v = (t >= d) ? ts[t - d] : 0;
        __syncthreads();
        ts[t] += v;
        __syncthreads();
    }
    u32 excl = ts[t] - tsum;
    boff[2 * t] = excl; boff[2 * t + 1] = excl + s0;
    bcur[2 * t] = excl; bcur[2 * t + 1] = excl + s0;
    __syncthreads();
    if (t < NB && bh[t]) bbs[t] = atomicAdd(&bcursor[t], bh[t]);
    if (t + 256 < NB && bh[t + 256]) bbs[t + 256] = atomicAdd(&bcursor[t + 256], bh[t + 256]);
    __syncthreads();
#pragma unroll
    for (int j = 0; j < CHUNK / 256; j++) {
        int e = base + j * 256 + t;
        if (e < ETOT) {
            int src, dst;
            edge_decode(ei, is64, e, src, dst);
            u32 pos = atomicAdd(&bcur[dst >> 8], 1u);
            stage[pos] = (u64)src | ((u64)dst << 32);
        }
    }
    __syncthreads();
    for (int i = t; i < chunk_n; i += 256) {
        u64 pr = stage[i];
        u32 b = (u32)(pr >> 32) >> 8;
        pairs[(size_t)bbs[b] + (i - boff[b])] = pr;
    }
}

__global__ __launch_bounds__(256) void sort_pass_kernel(
    const u64* __restrict__ pairs, const u32* __restrict__ bbase,
    int* __restrict__ srcs, int* __restrict__ offs)
{
    __shared__ u32 nh[256];
    __shared__ u32 ns[256];
    __shared__ u32 ncur[256];
    int t = threadIdx.x;
    int b = blockIdx.x;
    u32 beg = bbase[b], endp = bbase[b + 1];
    nh[t] = 0;
    __syncthreads();
    for (u32 i = beg + t; i < endp; i += 256) {
        u32 dst = (u32)(pairs[i] >> 32);
        atomicAdd(&nh[dst & 255], 1u);
    }
    __syncthreads();
    u32 cnt = nh[t];
    ns[t] = cnt; __syncthreads();
    for (int d = 1; d < 256; d <<= 1) {
        u32 v = (t >= d) ? ns[t - d] : 0;
        __syncthreads();
        ns[t] += v;
        __syncthreads();
    }
    u32 excl = ns[t] - cnt;
    int id = b * 256 + t;
    if (id <= NN) offs[id] = (int)(beg + excl);
    ncur[t] = excl;
    __syncthreads();
    for (u32 i = beg + t; i < endp; i += 256) {
        u64 pr = pairs[i];
        u32 loc = ((u32)(pr >> 32)) & 255;
        u32 p = atomicAdd(&ncur[loc], 1u);
        srcs[beg + p] = (int)(u32)pr;
    }
}

// ---------------- MFMA GEMM ----------------
__global__ __launch_bounds__(256) void mfma_gemm(
    const u16* __restrict__ A, int lda,
    const u16* __restrict__ Bt, int ldb,
    const float* __restrict__ bias,
    int nrows, int ksteps, int ncols,
    float* __restrict__ outF, u16* __restrict__ outB, u16* __restrict__ outB2, int ldo,
    int mode, const int* __restrict__ flags)
{
    int lane = threadIdx.x & 63;
    int wv = threadIdx.x >> 6;
    int wx = wv & 1, wy = wv >> 1;
    int l16 = lane & 15, quad = lane >> 4;
    int r0 = blockIdx.x * 128 + wx * 64;
    int n0 = wy * 64;

    Bt += (size_t)blockIdx.y * 128 * ldb;
    if (blockIdx.y) outB = outB2;

    f32x4 acc[4][4];
#pragma unroll
    for (int m = 0; m < 4; m++)
#pragma unroll
        for (int n = 0; n < 4; n++) acc[m][n] = (f32x4){0.f, 0.f, 0.f, 0.f};

    const u16* Ap = A + (size_t)(r0 + l16) * lda + quad * 8;
    const u16* Bp = Bt + (size_t)(n0 + l16) * ldb + quad * 8;

    for (int k = 0; k < ksteps; ++k) {
        bf16x8 af[4], bfr[4];
#pragma unroll
        for (int m = 0; m < 4; m++)
            af[m] = *(const bf16x8*)(Ap + (size_t)m * 16 * lda + k * 32);
#pragma unroll
        for (int n = 0; n < 4; n++)
            bfr[n] = *(const bf16x8*)(Bp + (size_t)n * 16 * ldb + k * 32);
#pragma unroll
        for (int m = 0; m < 4; m++)
#pragma unroll
            for (int n = 0; n < 4; n++)
                acc[m][n] = __builtin_amdgcn_mfma_f32_16x16x32_bf16(af[m], bfr[n], acc[m][n], 0, 0, 0);
    }

    int mk = mode;
    if (mk < 0) mk = flags[1] ? 2 : 1;

#pragma unroll
    for (int m = 0; m < 4; m++) {
#pragma unroll
        for (int n = 0; n < 4; n++) {
            int col = n0 + n * 16 + l16;
            float bb = (bias != nullptr && col < ncols) ? bias[col] : 0.f;
#pragma unroll
            for (int reg = 0; reg < 4; reg++) {
                int row = r0 + m * 16 + quad * 4 + reg;
                if (row < nrows && col < ncols) {
                    float v = acc[m][n][reg] + bb;
                    if (mk & 1) outF[(size_t)row * ldo + col] = v;
                    if (mk & 2) outB[(size_t)row * ldo + col] = f2bf(v);
                }
            }
        }
    }
}

// ---------------- fused GATv2 agg + bias + GELU + residual + LayerNorm ----------------
// 4 dst per wave: sub = lane>>4 picks dst, r = lane&15 owns ch r*8..r*8+7.
// One edge in flight per dst (4/wave); each channel owned by exactly one lane ->
// no accumulator cross-lane merge. Depth-2 src / depth-1 row prefetch.
__global__ __launch_bounds__(256) void gat_agg_kernel(
    const u16* __restrict__ hl, const u16* __restrict__ hr, const u16* __restrict__ hresb,
    const float* __restrict__ att, const float* __restrict__ bias,
    const float* __restrict__ gamma, const float* __restrict__ beta,
    const int* __restrict__ offs, const int* __restrict__ srcs,
    u16* __restrict__ outb)
{
    int lane = threadIdx.x & 63;
    int sub = lane >> 4;
    int r = lane & 15;
    int c0 = r * 8;
    int dst = (blockIdx.x * 4 + (threadIdx.x >> 6)) * 4 + sub;   // grid = NN/16 blocks

    int start = offs[dst];
    int deg = offs[dst + 1] - start;    // >= 1 (self loop)
    int dm = deg - 1;

    f32x2 hr2[4], av2[4];
    {
        uint4 q = *(const uint4*)(hr + ((size_t)dst << 7) + c0);
        hr2[0] = unpk(q.x); hr2[1] = unpk(q.y); hr2[2] = unpk(q.z); hr2[3] = unpk(q.w);
        float4 a0 = *(const float4*)&att[c0];
        float4 a1 = *(const float4*)&att[c0 + 4];
        av2[0] = (f32x2){a0.x, a0.y}; av2[1] = (f32x2){a0.z, a0.w};
        av2[2] = (f32x2){a1.x, a1.y}; av2[3] = (f32x2){a1.z, a1.w};
    }

    // wave-uniform iteration bound = max deg over the 4 sub-groups
    int md = deg;
    md = max(md, __shfl_xor(md, 16));
    md = max(md, __shfl_xor(md, 32));

    f32x2 acc2[4];
#pragma unroll
    for (int i = 0; i < 4; i++) acc2[i] = (f32x2){0.f, 0.f};
    float s = 0.f;

    // prefetch pipeline: src depth-2, row depth-1
    int src_c = srcs[start];                       // j = 0
    int src_n = srcs[start + (1 < dm ? 1 : dm)];   // j = 1 (clamped)
    uint4 q_c = *(const uint4*)(hl + ((size_t)src_c << 7) + c0);

    for (int j = 0; j < md; ++j) {
        int jn2 = j + 2; jn2 = jn2 < dm ? jn2 : dm;
        int src_n2 = srcs[start + jn2];                              // for j+2
        uint4 q_n = *(const uint4*)(hl + ((size_t)src_n << 7) + c0); // for j+1

        f32x2 h2[4];
        h2[0] = unpk(q_c.x); h2[1] = unpk(q_c.y);
        h2[2] = unpk(q_c.z); h2[3] = unpk(q_c.w);
        f32x2 p2 = (f32x2){0.f, 0.f};
#pragma unroll
        for (int i = 0; i < 4; i++) {
            f32x2 z = h2[i] + hr2[i];
            f32x2 lz = __builtin_elementwise_max(z, z * 0.2f);
            p2 = __builtin_elementwise_fma(av2[i], lz, p2);
        }
        float p = p2.x + p2.y;
        // head dot spread across the 4 lanes of a quad (same head): reduce
        p += __shfl_xor(p, 1);
        p += __shfl_xor(p, 2);
        float w = (j < deg) ? __expf(p) : 0.f;
        s += w;
        f32x2 w2 = (f32x2){w, w};
#pragma unroll
        for (int i = 0; i < 4; i++) acc2[i] = __builtin_elementwise_fma(w2, h2[i], acc2[i]);

        q_c = q_n; src_n = src_n2;
    }

    float inv = 1.f / s;
    float v[8];
    {
        float4 b0 = *(const float4*)&bias[c0];
        float4 b1 = *(const float4*)&bias[c0 + 4];
        float bb[8] = {b0.x,b0.y,b0.z,b0.w,b1.x,b1.y,b1.z,b1.w};
        uint4 qr = *(const uint4*)(hresb + ((size_t)dst << 7) + c0);
        f32x2 rr2[4] = {unpk(qr.x), unpk(qr.y), unpk(qr.z), unpk(qr.w)};
#pragma unroll
        for (int i = 0; i < 4; i++) {
            float t0 = fmaf(acc2[i].x, inv, bb[2*i]);
            float t1 = fmaf(acc2[i].y, inv, bb[2*i+1]);
            v[2*i]   = gelu_t(t0) + rr2[i].x;
            v[2*i+1] = gelu_t(t1) + rr2[i].y;
        }
    }

    // LayerNorm over 128 ch = the 16 lanes of this sub-group (offsets 1..8 stay in-group)
    float s1 = 0.f, s2 = 0.f;
#pragma unroll
    for (int k = 0; k < 8; k++) { s1 += v[k]; s2 = fmaf(v[k], v[k], s2); }
#pragma unroll
    for (int off = 1; off < 16; off <<= 1) {
        s1 += __shfl_xor(s1, off);
        s2 += __shfl_xor(s2, off);
    }
    float mu  = s1 * (1.f / 128.f);
    float var = s2 * (1.f / 128.f) - mu * mu;
    float rstd = rsqrtf(var + 1e-5f);

    float4 g0 = *(const float4*)&gamma[c0];
    float4 g1 = *(const float4*)&gamma[c0 + 4];
    float4 be0 = *(const float4*)&beta[c0];
    float4 be1 = *(const float4*)&beta[c0 + 4];
    float gg[8] = {g0.x,g0.y,g0.z,g0.w,g1.x,g1.y,g1.z,g1.w};
    float eb[8] = {be0.x,be0.y,be0.z,be0.w,be1.x,be1.y,be1.z,be1.w};
    float o[8];
#pragma unroll
    for (int k = 0; k < 8; k++) o[k] = fmaf((v[k] - mu) * rstd, gg[k], eb[k]);
    uint4 pk;
    pk.x = (u32)f2bf(o[0]) | ((u32)f2bf(o[1]) << 16);
    pk.y = (u32)f2bf(o[2]) | ((u32)f2bf(o[3]) << 16);
    pk.z = (u32)f2bf(o[4]) | ((u32)f2bf(o[5]) << 16);
    pk.w = (u32)f2bf(o[6]) | ((u32)f2bf(o[7]) << 16);
    *(uint4*)(outb + ((size_t)dst << 7) + c0) = pk;
}

// ---------------- launch ----------------
extern "C" void kernel_launch(void* const* d_in, const int* in_sizes, int n_in,
                              void* d_out, int out_size, void* d_ws, size_t ws_size,
                              hipStream_t stream) {
    const void* x  = d_in[0];
    const int*  ei = (const int*)d_in[1];

    char* ws = (char*)d_ws;
    size_t off = 0;
    auto alloc = [&](size_t bytes) -> void* {
        void* p = ws + off;
        off = (off + bytes + 511) & ~(size_t)511;
        return p;
    };
    u16*   xb      = (u16*)  alloc(((size_t)NN * MM + 8192) * 2);
    float* wv      = (float*)alloc((size_t)VTOT * 4);
    u16*   wbf     = (u16*)  alloc((size_t)BTOT * 2);
    u16*   h0b     = (u16*)  alloc((size_t)(NN + 64) * HID * 2);
    u16*   h1b     = (u16*)  alloc((size_t)(NN + 64) * HID * 2);
    u16*   hlb     = (u16*)  alloc((size_t)NN * HID * 2);
    u16*   hrb     = (u16*)  alloc((size_t)NN * HID * 2);
    int*   offs    = (int*)  alloc((size_t)(NN + 1) * 4);
    u32*   gbucket = (u32*)  alloc(512 * 4);
    u32*   bbase   = (u32*)  alloc(520 * 4);
    u32*   bcursor = (u32*)  alloc(520 * 4);
    int*   flags   = (int*)  alloc(512);
    int*   srcs    = (int*)  alloc(((size_t)ETOT + 64) * 4);
    u64*   pairs   = (u64*)  alloc((size_t)ETOT * 8);

    hipMemsetAsync(gbucket, 0, 512 * 4, stream);

    sniff_kernel<<<1, 64, 0, stream>>>((const u32*)ei, (const u32*)x, flags);

    normx_kernel<<<(NN * MM + 255) / 256, 256, 0, stream>>>(x, xb, NN * MM, flags);
    norm_vec_kernel<<<(VTOT + 255) / 256, 256, 0, stream>>>(
        d_in[3], d_in[6], d_in[7], d_in[12], d_in[13], d_in[10], d_in[11], d_in[14], d_in[15], d_in[17],
        wv, flags);
    norm_wt_kernel<<<(BTOT + 255) / 256, 256, 0, stream>>>(
        d_in[2], d_in[4], d_in[5], d_in[8], d_in[9], d_in[16], wbf, flags);

    const int EB = (ETOT + CHUNK - 1) / CHUNK;  // 416
    bucket_hist_kernel<<<EB, 256, 0, stream>>>(ei, flags, gbucket);
    bucket_scan_kernel<<<1, 256, 0, stream>>>(gbucket, bbase, bcursor);
    bin_pass_kernel<<<EB, 256, 0, stream>>>(ei, flags, bcursor, pairs);
    sort_pass_kernel<<<NB, 256, 0, stream>>>(pairs, bbase, srcs, offs);

    const int GB = (NN + 127) / 128;  // 782
    const int AB = NN / 16;           // 6250 blocks, 4 dst/wave x 4 waves

    // proj: h0b = bf16(x @ Wp + bp)   (K=40 padded to 64)
    mfma_gemm<<<dim3(GB, 1), 256, 0, stream>>>(xb, MM, wbf + BWp, 64, wv + Vbp,
                                               NN, 2, HID, nullptr, h0b, nullptr, HID, 2, flags);

    // layer 1: hl/hr in one dispatch
    mfma_gemm<<<dim3(GB, 2), 256, 0, stream>>>(h0b, HID, wbf + BW1l, HID, nullptr,
                                               NN, 4, HID, nullptr, hlb, hrb, HID, 2, flags);
    gat_agg_kernel<<<AB, 256, 0, stream>>>(hlb, hrb, h0b, wv + Vatt1, wv + Vb1,
                                           wv + Vg1, wv + Vbe1, offs, srcs, h1b);

    // layer 2
    mfma_gemm<<<dim3(GB, 2), 256, 0, stream>>>(h1b, HID, wbf + BW2l, HID, nullptr,
                                               NN, 4, HID, nullptr, hlb, hrb, HID, 2, flags);
    gat_agg_kernel<<<AB, 256, 0, stream>>>(hlb, hrb, h1b, wv + Vatt2, wv + Vb2,
                                           wv + Vg2, wv + Vbe2, offs, srcs, h0b);

    // final: out = h @ Wo + bo (dtype per flags)
    mfma_gemm<<<dim3(GB, 1), 256, 0, stream>>>(h0b, HID, wbf + BWo, HID, wv + Vbo,
                                               NN, 4, LAT, (float*)d_out, (u16*)d_out, nullptr, LAT, -1, flags);
}

// Round 8
// 485.734 us; speedup vs baseline: 2.1168x; 1.0511x over previous
//
#include <hip/hip_runtime.h>
#include <hip/hip_bf16.h>
#include <math.h>

#define NN   100000
#define EE   1600000
#define ETOT 1700000   // EE + NN self loops
#define MM   40
#define HID  128
#define LAT  64
#define NB   391       // ceil(NN/256) buckets of 256 nodes
#define CHUNK 4096     // edges per bin_pass block

typedef unsigned short u16;
typedef unsigned int   u32;
typedef unsigned long long u64;

typedef __attribute__((ext_vector_type(8))) short bf16x8;
typedef __attribute__((ext_vector_type(4))) float f32x4;
typedef __attribute__((ext_vector_type(2))) float f32x2;

__device__ __forceinline__ float bf2f(u16 a) {
    return __uint_as_float(((u32)a) << 16);
}
__device__ __forceinline__ u16 f2bf(float f) {
    u32 u = __float_as_uint(f);
    u32 r = (u + 0x7fffu + ((u >> 16) & 1u)) >> 16;
    return (u16)r;
}
__device__ __forceinline__ f32x2 unpk(u32 u) {
    f32x2 r;
    r.x = __uint_as_float(u << 16);
    r.y = __uint_as_float(u & 0xffff0000u);
    return r;
}
// tanh-form GELU via sigmoid: x * sigmoid(1.595769x + 0.0713548x^3); |err vs exact| <= ~3e-4
__device__ __forceinline__ float gelu_t(float x) {
    float x2 = x * x;
    float y = x * fmaf(0.0713548162726f, x2, 1.59576912161f);
    return x / (1.f + __expf(-y));
}

// f32 vector pack offsets (floats)
#define Vbp   0
#define Vatt1 128
#define Vb1   256
#define Vg1   384
#define Vbe1  512
#define Vatt2 640
#define Vb2   768
#define Vg2   896
#define Vbe2  1024
#define Vbo   1152
#define VTOT  1216

// bf16 transposed weight pack offsets (u16 elements)
#define BWp   0        // [128][64]  (K=40 zero-padded to 64)
#define BW1l  8192     // [128][128]
#define BW1r  24576    // adjacent to BW1l (gridDim.y=2 panel trick)
#define BW2l  40960
#define BW2r  57344
#define BWo   73728    // [64][128], padded to 128 rows (zeros)
#define BTOT  90112

// ---------------- dtype sniff ----------------
__global__ void sniff_kernel(const u32* __restrict__ ei_raw, const u32* __restrict__ x_raw,
                             int* __restrict__ flags) {
    if (threadIdx.x != 0 || blockIdx.x != 0) return;
    int allz = 1;
    for (int i = 1; i < 256; i += 2) allz &= (ei_raw[i] == 0u);
    flags[0] = allz;
    int bf_like = 0;
    for (int i = 0; i < 64; i++) {
        u16 lo = (u16)(x_raw[i] & 0xffffu);
        int e = (lo >> 7) & 0xFF;
        if (e >= 118 && e <= 133) bf_like++;
    }
    flags[1] = (bf_like >= 48) ? 1 : 0;
}

__device__ __forceinline__ void edge_decode(const int* __restrict__ ei, int is64, int e,
                                            int& src, int& dst) {
    if (e < EE) {
        src = is64 ? ei[2 * e] : ei[e];
        int idx = EE + e;
        dst = is64 ? ei[2 * idx] : ei[idx];
    } else {
        src = e - EE; dst = src;
    }
}

// ---------------- normalize x -> bf16 ----------------
__global__ void normx_kernel(const void* __restrict__ in, u16* __restrict__ out, int n,
                             const int* __restrict__ flags) {
    int i = blockIdx.x * 256 + threadIdx.x;
    if (i >= n) return;
    out[i] = flags[1] ? ((const u16*)in)[i] : f2bf(((const float*)in)[i]);
}

// ---------------- pack small vectors to f32 ----------------
__global__ void norm_vec_kernel(
    const void* p0, const void* p1, const void* p2, const void* p3, const void* p4,
    const void* p5, const void* p6, const void* p7, const void* p8, const void* p9,
    float* __restrict__ out, const int* __restrict__ flags)
{
    int i = blockIdx.x * 256 + threadIdx.x;
    if (i >= VTOT) return;
    const int offs[11] = {Vbp, Vatt1, Vb1, Vg1, Vbe1, Vatt2, Vb2, Vg2, Vbe2, Vbo, VTOT};
    const void* ps[10] = {p0,p1,p2,p3,p4,p5,p6,p7,p8,p9};
    int s = 0;
#pragma unroll
    for (int k = 1; k < 10; k++) s += (i >= offs[k]) ? 1 : 0;
    int j = i - offs[s];
    const void* p = ps[s];
    out[i] = flags[1] ? bf2f(((const u16*)p)[j]) : ((const float*)p)[j];
}

// ---------------- transpose weights to bf16 Wt[n][k] ----------------
__global__ void norm_wt_kernel(
    const void* w0, const void* w1, const void* w2, const void* w3, const void* w4,
    const void* w5, u16* __restrict__ out, const int* __restrict__ flags)
{
    int i = blockIdx.x * 256 + threadIdx.x;
    if (i >= BTOT) return;
    const int offs[7] = {BWp, BW1l, BW1r, BW2l, BW2r, BWo, BTOT};
    const int Ks[6]   = {40, 128, 128, 128, 128, 128};
    const int Ncs[6]  = {128, 128, 128, 128, 128, 64};
    const int Kps[6]  = {64, 128, 128, 128, 128, 128};
    const void* ps[6] = {w0,w1,w2,w3,w4,w5};
    int s = 0;
#pragma unroll
    for (int k = 1; k < 6; k++) s += (i >= offs[k]) ? 1 : 0;
    int j = i - offs[s];
    int Kp = Kps[s];
    int n = j / Kp, k = j % Kp;
    u16 v = 0;
    if (k < Ks[s] && n < Ncs[s]) {
        const void* p = ps[s];
        int src = k * Ncs[s] + n;
        v = flags[1] ? ((const u16*)p)[src] : f2bf(((const float*)p)[src]);
    }
    out[i] = v;
}

// ---------------- CSR build: 2-pass LDS-binned counting sort ----------------
__global__ __launch_bounds__(256) void bucket_hist_kernel(
    const int* __restrict__ ei, const int* __restrict__ flags, u32* __restrict__ gbucket)
{
    __shared__ u32 h[512];
    int t = threadIdx.x;
    h[t] = 0; h[t + 256] = 0;
    __syncthreads();
    int is64 = flags[0];
    int base = blockIdx.x * CHUNK;
#pragma unroll
    for (int j = 0; j < CHUNK / 256; j++) {
        int e = base + j * 256 + t;
        if (e < ETOT) {
            int src, dst;
            edge_decode(ei, is64, e, src, dst);
            atomicAdd(&h[dst >> 8], 1u);
        }
    }
    __syncthreads();
    if (h[t])       atomicAdd(&gbucket[t], h[t]);
    if (h[t + 256]) atomicAdd(&gbucket[t + 256], h[t + 256]);
}

__global__ __launch_bounds__(256) void bucket_scan_kernel(
    const u32* __restrict__ gbucket, u32* __restrict__ bbase, u32* __restrict__ bcursor)
{
    __shared__ u32 ts[256];
    int t = threadIdx.x;
    u32 s0 = (2 * t     < NB) ? gbucket[2 * t]     : 0;
    u32 s1 = (2 * t + 1 < NB) ? gbucket[2 * t + 1] : 0;
    u32 tsum = s0 + s1;
    ts[t] = tsum; __syncthreads();
    for (int d = 1; d < 256; d <<= 1) {
        u32 v = (t >= d) ? ts[t - d] : 0;
        __syncthreads();
        ts[t] += v;
        __syncthreads();
    }
    u32 excl = ts[t] - tsum;
    bbase[2 * t] = excl;          bcursor[2 * t] = excl;
    bbase[2 * t + 1] = excl + s0; bcursor[2 * t + 1] = excl + s0;
    if (2 * t == NB - 1 || 2 * t + 1 == NB - 1) bbase[NB] = ETOT;
}

__global__ __launch_bounds__(256) void bin_pass_kernel(
    const int* __restrict__ ei, const int* __restrict__ flags,
    u32* __restrict__ bcursor, u64* __restrict__ pairs)
{
    __shared__ u32 bh[512];
    __shared__ u32 boff[512];
    __shared__ u32 bbs[512];
    __shared__ u32 bcur[512];
    __shared__ u64 stage[CHUNK];
    __shared__ u32 ts[256];

    int t = threadIdx.x;
    bh[t] = 0; bh[t + 256] = 0;
    __syncthreads();
    int is64 = flags[0];
    int base = blockIdx.x * CHUNK;
    int chunk_n = ETOT - base; if (chunk_n > CHUNK) chunk_n = CHUNK;

#pragma unroll
    for (int j = 0; j < CHUNK / 256; j++) {
        int e = base + j * 256 + t;
        if (e < ETOT) {
            int src, dst;
            edge_decode(ei, is64, e, src, dst);
            atomicAdd(&bh[dst >> 8], 1u);
        }
    }
    __syncthreads();
    u32 s0 = bh[2 * t], s1 = bh[2 * t + 1];
    u32 tsum = s0 + s1;
    ts[t] = tsum; __syncthreads();
    for (int d = 1; d < 256; d <<= 1) {
        u32 v = (t >= d) ? ts[t - d] : 0;
        __syncthreads();
        ts[t] += v;
        __syncthreads();
    }
    u32 excl = ts[t] - tsum;
    boff[2 * t] = excl; boff[2 * t + 1] = excl + s0;
    bcur[2 * t] = excl; bcur[2 * t + 1] = excl + s0;
    __syncthreads();
    if (t < NB && bh[t]) bbs[t] = atomicAdd(&bcursor[t], bh[t]);
    if (t + 256 < NB && bh[t + 256]) bbs[t + 256] = atomicAdd(&bcursor[t + 256], bh[t + 256]);
    __syncthreads();
#pragma unroll
    for (int j = 0; j < CHUNK / 256; j++) {
        int e = base + j * 256 + t;
        if (e < ETOT) {
            int src, dst;
            edge_decode(ei, is64, e, src, dst);
            u32 pos = atomicAdd(&bcur[dst >> 8], 1u);
            stage[pos] = (u64)src | ((u64)dst << 32);
        }
    }
    __syncthreads();
    for (int i = t; i < chunk_n; i += 256) {
        u64 pr = stage[i];
        u32 b = (u32)(pr >> 32) >> 8;
        pairs[(size_t)bbs[b] + (i - boff[b])] = pr;
    }
}

__global__ __launch_bounds__(256) void sort_pass_kernel(
    const u64* __restrict__ pairs, const u32* __restrict__ bbase,
    int* __restrict__ srcs, int* __restrict__ offs)
{
    __shared__ u32 nh[256];
    __shared__ u32 ns[256];
    __shared__ u32 ncur[256];
    int t = threadIdx.x;
    int b = blockIdx.x;
    u32 beg = bbase[b], endp = bbase[b + 1];
    nh[t] = 0;
    __syncthreads();
    for (u32 i = beg + t; i < endp; i += 256) {
        u32 dst = (u32)(pairs[i] >> 32);
        atomicAdd(&nh[dst & 255], 1u);
    }
    __syncthreads();
    u32 cnt = nh[t];
    ns[t] = cnt; __syncthreads();
    for (int d = 1; d < 256; d <<= 1) {
        u32 v = (t >= d) ? ns[t - d] : 0;
        __syncthreads();
        ns[t] += v;
        __syncthreads();
    }
    u32 excl = ns[t] - cnt;
    int id = b * 256 + t;
    if (id <= NN) offs[id] = (int)(beg + excl);
    ncur[t] = excl;
    __syncthreads();
    for (u32 i = beg + t; i < endp; i += 256) {
        u64 pr = pairs[i];
        u32 loc = ((u32)(pr >> 32)) & 255;
        u32 p = atomicAdd(&ncur[loc], 1u);
        srcs[beg + p] = (int)(u32)pr;
    }
}

// ---------------- MFMA GEMM ----------------
__global__ __launch_bounds__(256) void mfma_gemm(
    const u16* __restrict__ A, int lda,
    const u16* __restrict__ Bt, int ldb,
    const float* __restrict__ bias,
    int nrows, int ksteps, int ncols,
    float* __restrict__ outF, u16* __restrict__ outB, u16* __restrict__ outB2, int ldo,
    int mode, const int* __restrict__ flags)
{
    int lane = threadIdx.x & 63;
    int wv = threadIdx.x >> 6;
    int wx = wv & 1, wy = wv >> 1;
    int l16 = lane & 15, quad = lane >> 4;
    int r0 = blockIdx.x * 128 + wx * 64;
    int n0 = wy * 64;

    Bt += (size_t)blockIdx.y * 128 * ldb;
    if (blockIdx.y) outB = outB2;

    f32x4 acc[4][4];
#pragma unroll
    for (int m = 0; m < 4; m++)
#pragma unroll
        for (int n = 0; n < 4; n++) acc[m][n] = (f32x4){0.f, 0.f, 0.f, 0.f};

    const u16* Ap = A + (size_t)(r0 + l16) * lda + quad * 8;
    const u16* Bp = Bt + (size_t)(n0 + l16) * ldb + quad * 8;

    for (int k = 0; k < ksteps; ++k) {
        bf16x8 af[4], bfr[4];
#pragma unroll
        for (int m = 0; m < 4; m++)
            af[m] = *(const bf16x8*)(Ap + (size_t)m * 16 * lda + k * 32);
#pragma unroll
        for (int n = 0; n < 4; n++)
            bfr[n] = *(const bf16x8*)(Bp + (size_t)n * 16 * ldb + k * 32);
#pragma unroll
        for (int m = 0; m < 4; m++)
#pragma unroll
            for (int n = 0; n < 4; n++)
                acc[m][n] = __builtin_amdgcn_mfma_f32_16x16x32_bf16(af[m], bfr[n], acc[m][n], 0, 0, 0);
    }

    int mk = mode;
    if (mk < 0) mk = flags[1] ? 2 : 1;

#pragma unroll
    for (int m = 0; m < 4; m++) {
#pragma unroll
        for (int n = 0; n < 4; n++) {
            int col = n0 + n * 16 + l16;
            float bb = (bias != nullptr && col < ncols) ? bias[col] : 0.f;
#pragma unroll
            for (int reg = 0; reg < 4; reg++) {
                int row = r0 + m * 16 + quad * 4 + reg;
                if (row < nrows && col < ncols) {
                    float v = acc[m][n][reg] + bb;
                    if (mk & 1) outF[(size_t)row * ldo + col] = v;
                    if (mk & 2) outB[(size_t)row * ldo + col] = f2bf(v);
                }
            }
        }
    }
}

// ---------------- fused GATv2 agg + bias + GELU + residual + LayerNorm ----------------
// 4 dst per wave (sub = lane>>4), lane r = lane&15 owns ch r*8..r*8+7.
// 2 edges per dst in flight per iteration (8 gathers/wave outstanding incl. prefetch).
__global__ __launch_bounds__(256) void gat_agg_kernel(
    const u16* __restrict__ hl, const u16* __restrict__ hr, const u16* __restrict__ hresb,
    const float* __restrict__ att, const float* __restrict__ bias,
    const float* __restrict__ gamma, const float* __restrict__ beta,
    const int* __restrict__ offs, const int* __restrict__ srcs,
    u16* __restrict__ outb)
{
    int lane = threadIdx.x & 63;
    int sub = lane >> 4;
    int r = lane & 15;
    int c0 = r * 8;
    int dst = (blockIdx.x * 4 + (threadIdx.x >> 6)) * 4 + sub;   // grid = NN/16 blocks

    int start = offs[dst];
    int deg = offs[dst + 1] - start;    // >= 1 (self loop)
    int dm = deg - 1;

    f32x2 hr2[4], av2[4];
    {
        uint4 q = *(const uint4*)(hr + ((size_t)dst << 7) + c0);
        hr2[0] = unpk(q.x); hr2[1] = unpk(q.y); hr2[2] = unpk(q.z); hr2[3] = unpk(q.w);
        float4 a0 = *(const float4*)&att[c0];
        float4 a1 = *(const float4*)&att[c0 + 4];
        av2[0] = (f32x2){a0.x, a0.y}; av2[1] = (f32x2){a0.z, a0.w};
        av2[2] = (f32x2){a1.x, a1.y}; av2[3] = (f32x2){a1.z, a1.w};
    }

    // wave-uniform iteration bound = max deg over the 4 sub-groups
    int md = deg;
    md = max(md, __shfl_xor(md, 16));
    md = max(md, __shfl_xor(md, 32));

    f32x2 acc2[4];
#pragma unroll
    for (int i = 0; i < 4; i++) acc2[i] = (f32x2){0.f, 0.f};
    float s = 0.f;

    // prefetch: edges 0,1 rows; srcs for edges 2,3
    int sa = srcs[start];
    int sb = srcs[start + (1 < dm ? 1 : dm)];
    uint4 qa = *(const uint4*)(hl + ((size_t)sa << 7) + c0);
    uint4 qb = *(const uint4*)(hl + ((size_t)sb << 7) + c0);
    int sna = srcs[start + (2 < dm ? 2 : dm)];
    int snb = srcs[start + (3 < dm ? 3 : dm)];

    int mi = (md + 1) >> 1;
    for (int j = 0; j < mi; ++j) {
        // srcs for iteration j+2 (edges 2j+4, 2j+5)
        int e4 = 2 * j + 4, e5 = 2 * j + 5;
        int sna2 = srcs[start + (e4 < dm ? e4 : dm)];
        int snb2 = srcs[start + (e5 < dm ? e5 : dm)];
        // rows for iteration j+1
        uint4 qna = *(const uint4*)(hl + ((size_t)sna << 7) + c0);
        uint4 qnb = *(const uint4*)(hl + ((size_t)snb << 7) + c0);

        f32x2 ha[4], hb[4];
        ha[0] = unpk(qa.x); ha[1] = unpk(qa.y); ha[2] = unpk(qa.z); ha[3] = unpk(qa.w);
        hb[0] = unpk(qb.x); hb[1] = unpk(qb.y); hb[2] = unpk(qb.z); hb[3] = unpk(qb.w);
        f32x2 pa2 = (f32x2){0.f, 0.f};
        f32x2 pb2 = (f32x2){0.f, 0.f};
#pragma unroll
        for (int i = 0; i < 4; i++) {
            f32x2 za = ha[i] + hr2[i];
            f32x2 zb = hb[i] + hr2[i];
            f32x2 la = __builtin_elementwise_max(za, za * 0.2f);
            f32x2 lb = __builtin_elementwise_max(zb, zb * 0.2f);
            pa2 = __builtin_elementwise_fma(av2[i], la, pa2);
            pb2 = __builtin_elementwise_fma(av2[i], lb, pb2);
        }
        float pa = pa2.x + pa2.y;
        float pb = pb2.x + pb2.y;
        pa += __shfl_xor(pa, 1); pb += __shfl_xor(pb, 1);
        pa += __shfl_xor(pa, 2); pb += __shfl_xor(pb, 2);
        int e0 = 2 * j, e1 = 2 * j + 1;
        float wa = (e0 < deg) ? __expf(pa) : 0.f;
        float wb = (e1 < deg) ? __expf(pb) : 0.f;
        s += wa + wb;
        f32x2 wa2 = (f32x2){wa, wa};
        f32x2 wb2 = (f32x2){wb, wb};
#pragma unroll
        for (int i = 0; i < 4; i++)
            acc2[i] = __builtin_elementwise_fma(wa2, ha[i],
                      __builtin_elementwise_fma(wb2, hb[i], acc2[i]));

        qa = qna; qb = qnb; sna = sna2; snb = snb2;
    }

    float inv = 1.f / s;
    float v[8];
    {
        float4 b0 = *(const float4*)&bias[c0];
        float4 b1 = *(const float4*)&bias[c0 + 4];
        float bb[8] = {b0.x,b0.y,b0.z,b0.w,b1.x,b1.y,b1.z,b1.w};
        uint4 qr = *(const uint4*)(hresb + ((size_t)dst << 7) + c0);
        f32x2 rr2[4] = {unpk(qr.x), unpk(qr.y), unpk(qr.z), unpk(qr.w)};
#pragma unroll
        for (int i = 0; i < 4; i++) {
            float t0 = fmaf(acc2[i].x, inv, bb[2*i]);
            float t1 = fmaf(acc2[i].y, inv, bb[2*i+1]);
            v[2*i]   = gelu_t(t0) + rr2[i].x;
            v[2*i+1] = gelu_t(t1) + rr2[i].y;
        }
    }

    // LayerNorm over 128 ch = 16 lanes of this sub-group (offsets 1..8 stay in-group)
    float s1 = 0.f, s2 = 0.f;
#pragma unroll
    for (int k = 0; k < 8; k++) { s1 += v[k]; s2 = fmaf(v[k], v[k], s2); }
#pragma unroll
    for (int off = 1; off < 16; off <<= 1) {
        s1 += __shfl_xor(s1, off);
        s2 += __shfl_xor(s2, off);
    }
    float mu  = s1 * (1.f / 128.f);
    float var = s2 * (1.f / 128.f) - mu * mu;
    float rstd = rsqrtf(var + 1e-5f);

    float4 g0 = *(const float4*)&gamma[c0];
    float4 g1 = *(const float4*)&gamma[c0 + 4];
    float4 be0 = *(const float4*)&beta[c0];
    float4 be1 = *(const float4*)&beta[c0 + 4];
    float gg[8] = {g0.x,g0.y,g0.z,g0.w,g1.x,g1.y,g1.z,g1.w};
    float eb[8] = {be0.x,be0.y,be0.z,be0.w,be1.x,be1.y,be1.z,be1.w};
    float o[8];
#pragma unroll
    for (int k = 0; k < 8; k++) o[k] = fmaf((v[k] - mu) * rstd, gg[k], eb[k]);
    uint4 pk;
    pk.x = (u32)f2bf(o[0]) | ((u32)f2bf(o[1]) << 16);
    pk.y = (u32)f2bf(o[2]) | ((u32)f2bf(o[3]) << 16);
    pk.z = (u32)f2bf(o[4]) | ((u32)f2bf(o[5]) << 16);
    pk.w = (u32)f2bf(o[6]) | ((u32)f2bf(o[7]) << 16);
    *(uint4*)(outb + ((size_t)dst << 7) + c0) = pk;
}

// ---------------- launch ----------------
extern "C" void kernel_launch(void* const* d_in, const int* in_sizes, int n_in,
                              void* d_out, int out_size, void* d_ws, size_t ws_size,
                              hipStream_t stream) {
    const void* x  = d_in[0];
    const int*  ei = (const int*)d_in[1];

    char* ws = (char*)d_ws;
    size_t off = 0;
    auto alloc = [&](size_t bytes) -> void* {
        void* p = ws + off;
        off = (off + bytes + 511) & ~(size_t)511;
        return p;
    };
    u16*   xb      = (u16*)  alloc(((size_t)NN * MM + 8192) * 2);
    float* wv      = (float*)alloc((size_t)VTOT * 4);
    u16*   wbf     = (u16*)  alloc((size_t)BTOT * 2);
    u16*   h0b     = (u16*)  alloc((size_t)(NN + 64) * HID * 2);
    u16*   h1b     = (u16*)  alloc((size_t)(NN + 64) * HID * 2);
    u16*   hlb     = (u16*)  alloc((size_t)NN * HID * 2);
    u16*   hrb     = (u16*)  alloc((size_t)NN * HID * 2);
    int*   offs    = (int*)  alloc((size_t)(NN + 1) * 4);
    u32*   gbucket = (u32*)  alloc(512 * 4);
    u32*   bbase   = (u32*)  alloc(520 * 4);
    u32*   bcursor = (u32*)  alloc(520 * 4);
    int*   flags   = (int*)  alloc(512);
    int*   srcs    = (int*)  alloc(((size_t)ETOT + 64) * 4);
    u64*   pairs   = (u64*)  alloc((size_t)ETOT * 8);

    hipMemsetAsync(gbucket, 0, 512 * 4, stream);

    sniff_kernel<<<1, 64, 0, stream>>>((const u32*)ei, (const u32*)x, flags);

    normx_kernel<<<(NN * MM + 255) / 256, 256, 0, stream>>>(x, xb, NN * MM, flags);
    norm_vec_kernel<<<(VTOT + 255) / 256, 256, 0, stream>>>(
        d_in[3], d_in[6], d_in[7], d_in[12], d_in[13], d_in[10], d_in[11], d_in[14], d_in[15], d_in[17],
        wv, flags);
    norm_wt_kernel<<<(BTOT + 255) / 256, 256, 0, stream>>>(
        d_in[2], d_in[4], d_in[5], d_in[8], d_in[9], d_in[16], wbf, flags);

    const int EB = (ETOT + CHUNK - 1) / CHUNK;  // 416
    bucket_hist_kernel<<<EB, 256, 0, stream>>>(ei, flags, gbucket);
    bucket_scan_kernel<<<1, 256, 0, stream>>>(gbucket, bbase, bcursor);
    bin_pass_kernel<<<EB, 256, 0, stream>>>(ei, flags, bcursor, pairs);
    sort_pass_kernel<<<NB, 256, 0, stream>>>(pairs, bbase, srcs, offs);

    const int GB = (NN + 127) / 128;  // 782
    const int AB = NN / 16;           // 6250 blocks, 4 dst/wave x 4 waves

    // proj: h0b = bf16(x @ Wp + bp)   (K=40 padded to 64)
    mfma_gemm<<<dim3(GB, 1), 256, 0, stream>>>(xb, MM, wbf + BWp, 64, wv + Vbp,
                                               NN, 2, HID, nullptr, h0b, nullptr, HID, 2, flags);

    // layer 1: hl/hr in one dispatch
    mfma_gemm<<<dim3(GB, 2), 256, 0, stream>>>(h0b, HID, wbf + BW1l, HID, nullptr,
                                               NN, 4, HID, nullptr, hlb, hrb, HID, 2, flags);
    gat_agg_kernel<<<AB, 256, 0, stream>>>(hlb, hrb, h0b, wv + Vatt1, wv + Vb1,
                                           wv + Vg1, wv + Vbe1, offs, srcs, h1b);

    // layer 2
    mfma_gemm<<<dim3(GB, 2), 256, 0, stream>>>(h1b, HID, wbf + BW2l, HID, nullptr,
                                               NN, 4, HID, nullptr, hlb, hrb, HID, 2, flags);
    gat_agg_kernel<<<AB, 256, 0, stream>>>(hlb, hrb, h1b, wv + Vatt2, wv + Vb2,
                                           wv + Vg2, wv + Vbe2, offs, srcs, h0b);

    // final: out = h @ Wo + bo (dtype per flags)
    mfma_gemm<<<dim3(GB, 1), 256, 0, stream>>>(h0b, HID, wbf + BWo, HID, wv + Vbo,
                                               NN, 4, LAT, (float*)d_out, (u16*)d_out, nullptr, LAT, -1, flags);
}